// Round 6
// baseline (702.642 us; speedup 1.0000x reference)
//
#include <hip/hip_runtime.h>

// ---------------- problem dims (fixed by reference) ----------------
// N=50000, E=640000, DIN=128, DH=256, DOUT=128

typedef float floatx4 __attribute__((ext_vector_type(4)));
typedef short bf16x8 __attribute__((ext_vector_type(8)));

__device__ inline unsigned short f2bf(float f) {
    unsigned u = __float_as_uint(f);
    unsigned r = (u + 0x7fffu + ((u >> 16) & 1u)) >> 16;  // RNE
    return (unsigned short)r;
}
__device__ inline float bf2f_lo(unsigned v) { return __uint_as_float(v << 16); }
__device__ inline float bf2f_hi(unsigned v) { return __uint_as_float(v & 0xffff0000u); }

// ================= CSR build =================
__global__ void hist_kernel(const int* __restrict__ dst, int* __restrict__ cnt, int E) {
    int i = blockIdx.x * blockDim.x + threadIdx.x;
    if (i < E) atomicAdd(&cnt[dst[i]], 1);
}

#define SCAN_CHUNK 2048

__global__ __launch_bounds__(256) void scan_blocksums(const int* __restrict__ cnt,
                                                      int* __restrict__ bsum, int N) {
    __shared__ int sh[256];
    int t = threadIdx.x;
    int base = blockIdx.x * SCAN_CHUNK + t * 8;
    int s = 0;
#pragma unroll
    for (int i = 0; i < 8; i++) {
        int idx = base + i;
        if (idx < N) s += cnt[idx];
    }
    sh[t] = s;
    __syncthreads();
    for (int off = 1; off < 256; off <<= 1) {
        int v = (t >= off) ? sh[t - off] : 0;
        __syncthreads();
        sh[t] += v;
        __syncthreads();
    }
    if (t == 255) bsum[blockIdx.x] = sh[255];
}

__global__ __launch_bounds__(256) void scan_bsums(const int* __restrict__ bsum,
                                                  int* __restrict__ boff, int NB,
                                                  int* __restrict__ rowptr, int N, int E) {
    __shared__ int sh[256];
    int t = threadIdx.x;
    int v = (t < NB) ? bsum[t] : 0;
    sh[t] = v;
    __syncthreads();
    for (int off = 1; off < 256; off <<= 1) {
        int u = (t >= off) ? sh[t - off] : 0;
        __syncthreads();
        sh[t] += u;
        __syncthreads();
    }
    if (t < NB) boff[t] = sh[t] - v;
    if (t == 0) rowptr[N] = E;
}

__global__ __launch_bounds__(256) void scan_final(const int* __restrict__ cnt,
                                                  const int* __restrict__ boff,
                                                  int* __restrict__ rowptr,
                                                  int* __restrict__ cursor,
                                                  float* __restrict__ invdeg, int N) {
    __shared__ int sh[256];
    int t = threadIdx.x;
    int base = blockIdx.x * SCAN_CHUNK + t * 8;
    int c[8];
    int s = 0;
#pragma unroll
    for (int i = 0; i < 8; i++) {
        int idx = base + i;
        c[i] = (idx < N) ? cnt[idx] : 0;
        s += c[i];
    }
    sh[t] = s;
    __syncthreads();
    for (int off = 1; off < 256; off <<= 1) {
        int v = (t >= off) ? sh[t - off] : 0;
        __syncthreads();
        sh[t] += v;
        __syncthreads();
    }
    int run = boff[blockIdx.x] + sh[t] - s;
#pragma unroll
    for (int i = 0; i < 8; i++) {
        int idx = base + i;
        if (idx < N) {
            rowptr[idx] = run;
            cursor[idx] = run;
            invdeg[idx] = 1.0f / (float)(c[i] > 1 ? c[i] : 1);
            run += c[i];
        }
    }
}

__global__ void scatter_kernel(const int* __restrict__ src, const int* __restrict__ dst,
                               int* __restrict__ cursor, int* __restrict__ col, int E) {
    int i = blockIdx.x * blockDim.x + threadIdx.x;
    if (i < E) {
        int p = atomicAdd(&cursor[dst[i]], 1);
        col[p] = src[i];
    }
}

// ================= fused weight prep =================
// WtC [512,256]: rows 0-255 = [W1l;W1r]^T (u), rows 256-511 = [0;Wsk]^T (s)
// Wt2 [256,512]  ;  Wt3 [256,256]: rows 0-127 W3l^T, 128-255 W3r^T
// biasC [512] = [b1l | bsk]
__global__ void prep_weights(const float* __restrict__ W1l, const float* __restrict__ W1r,
                             const float* __restrict__ Wsk, const float* __restrict__ W2l,
                             const float* __restrict__ W2r, const float* __restrict__ W3l,
                             const float* __restrict__ W3r, const float* __restrict__ b1l,
                             const float* __restrict__ bsk,
                             unsigned short* __restrict__ WtC, unsigned short* __restrict__ Wt2,
                             unsigned short* __restrict__ Wt3, float* __restrict__ biasC) {
    int i = blockIdx.x * blockDim.x + threadIdx.x;
    if (i < 32768) {                        // W1l [128,256]
        int k = i >> 8, n = i & 255;
        WtC[n * 256 + k] = f2bf(W1l[i]);
    } else if (i < 65536) {                 // W1r
        int j = i - 32768, k = j >> 8, n = j & 255;
        WtC[n * 256 + 128 + k] = f2bf(W1r[j]);
    } else if (i < 98304) {                 // Wsk -> rows 256-511, k-half 128-255
        int j = i - 65536, k = j >> 8, n = j & 255;
        WtC[(256 + n) * 256 + 128 + k] = f2bf(Wsk[j]);
    } else if (i < 131072) {                // zero-fill rows 256-511, k-half 0-127
        int j = i - 98304, k = j >> 8, n = j & 255;
        WtC[(256 + n) * 256 + k] = 0;
    } else if (i < 196608) {                // W2l [256,256]
        int j = i - 131072, k = j >> 8, n = j & 255;
        Wt2[n * 512 + k] = f2bf(W2l[j]);
    } else if (i < 262144) {                // W2r
        int j = i - 196608, k = j >> 8, n = j & 255;
        Wt2[n * 512 + 256 + k] = f2bf(W2r[j]);
    } else if (i < 294912) {                // W3l [256,128]
        int j = i - 262144, k = j >> 7, n = j & 127;
        Wt3[n * 256 + k] = f2bf(W3l[j]);
    } else if (i < 327680) {                // W3r
        int j = i - 294912, k = j >> 7, n = j & 127;
        Wt3[(128 + n) * 256 + k] = f2bf(W3r[j]);
    } else if (i < 328192) {                // biasC [512]
        int j = i - 327680;
        biasC[j] = (j < 256) ? b1l[j] : bsk[j - 256];
    }
}

__global__ void cvt_x_kernel(const float* __restrict__ x, unsigned short* __restrict__ A1cat, int total) {
    int i = blockIdx.x * blockDim.x + threadIdx.x;
    if (i >= total) return;
    int r = i >> 7, c = i & 127;
    A1cat[(size_t)r * 256 + 128 + c] = f2bf(x[i]);
}

// ================= CSR mean aggregation v2 =================
__global__ __launch_bounds__(256) void agg_bf16_v2(const int* __restrict__ rowptr,
                                                   const int* __restrict__ col,
                                                   const float* __restrict__ invdeg,
                                                   const unsigned short* __restrict__ X, int xstride,
                                                   unsigned short* __restrict__ out, int ostride, int N) {
    int wid = (blockIdx.x * blockDim.x + threadIdx.x) >> 6;
    int lane = threadIdx.x & 63;
    if (wid >= N) return;
    int half = lane >> 5;
    int sub = lane & 31;
    int off = blockIdx.y * 128 + sub * 4;
    const unsigned short* Xo = X + off;
    int s = rowptr[wid], e = rowptr[wid + 1];
    float a0 = 0.f, a1 = 0.f, a2 = 0.f, a3 = 0.f;
    int j = s + half;
    for (; j + 6 < e; j += 8) {
        int c0 = col[j], c1 = col[j + 2], c2 = col[j + 4], c3 = col[j + 6];
        uint2 v0 = *(const uint2*)(Xo + (size_t)c0 * xstride);
        uint2 v1 = *(const uint2*)(Xo + (size_t)c1 * xstride);
        uint2 v2 = *(const uint2*)(Xo + (size_t)c2 * xstride);
        uint2 v3 = *(const uint2*)(Xo + (size_t)c3 * xstride);
        a0 += (bf2f_lo(v0.x) + bf2f_lo(v1.x)) + (bf2f_lo(v2.x) + bf2f_lo(v3.x));
        a1 += (bf2f_hi(v0.x) + bf2f_hi(v1.x)) + (bf2f_hi(v2.x) + bf2f_hi(v3.x));
        a2 += (bf2f_lo(v0.y) + bf2f_lo(v1.y)) + (bf2f_lo(v2.y) + bf2f_lo(v3.y));
        a3 += (bf2f_hi(v0.y) + bf2f_hi(v1.y)) + (bf2f_hi(v2.y) + bf2f_hi(v3.y));
    }
    for (; j < e; j += 2) {
        int c = col[j];
        uint2 v = *(const uint2*)(Xo + (size_t)c * xstride);
        a0 += bf2f_lo(v.x); a1 += bf2f_hi(v.x);
        a2 += bf2f_lo(v.y); a3 += bf2f_hi(v.y);
    }
    a0 += __shfl_xor(a0, 32, 64);
    a1 += __shfl_xor(a1, 32, 64);
    a2 += __shfl_xor(a2, 32, 64);
    a3 += __shfl_xor(a3, 32, 64);
    if (half == 0) {
        float inv = invdeg[wid];
        ushort4 o;
        o.x = f2bf(a0 * inv); o.y = f2bf(a1 * inv);
        o.z = f2bf(a2 * inv); o.w = f2bf(a3 * inv);
        *(ushort4*)(out + (size_t)wid * ostride + off) = o;
    }
}

// final: out = mean-agg(T bf16 [N,128]) + R fp32 [N,128], fp32 out
__global__ __launch_bounds__(256) void agg_final_v2(const int* __restrict__ rowptr,
                                                    const int* __restrict__ col,
                                                    const float* __restrict__ invdeg,
                                                    const unsigned short* __restrict__ T,
                                                    const float* __restrict__ R,
                                                    float* __restrict__ out, int N) {
    int wid = (blockIdx.x * blockDim.x + threadIdx.x) >> 6;
    int lane = threadIdx.x & 63;
    if (wid >= N) return;
    int half = lane >> 5;
    int sub = lane & 31;
    const unsigned short* To = T + sub * 4;
    int s = rowptr[wid], e = rowptr[wid + 1];
    float a0 = 0.f, a1 = 0.f, a2 = 0.f, a3 = 0.f;
    int j = s + half;
    for (; j + 6 < e; j += 8) {
        int c0 = col[j], c1 = col[j + 2], c2 = col[j + 4], c3 = col[j + 6];
        uint2 v0 = *(const uint2*)(To + (size_t)c0 * 128);
        uint2 v1 = *(const uint2*)(To + (size_t)c1 * 128);
        uint2 v2 = *(const uint2*)(To + (size_t)c2 * 128);
        uint2 v3 = *(const uint2*)(To + (size_t)c3 * 128);
        a0 += (bf2f_lo(v0.x) + bf2f_lo(v1.x)) + (bf2f_lo(v2.x) + bf2f_lo(v3.x));
        a1 += (bf2f_hi(v0.x) + bf2f_hi(v1.x)) + (bf2f_hi(v2.x) + bf2f_hi(v3.x));
        a2 += (bf2f_lo(v0.y) + bf2f_lo(v1.y)) + (bf2f_lo(v2.y) + bf2f_lo(v3.y));
        a3 += (bf2f_hi(v0.y) + bf2f_hi(v1.y)) + (bf2f_hi(v2.y) + bf2f_hi(v3.y));
    }
    for (; j < e; j += 2) {
        int c = col[j];
        uint2 v = *(const uint2*)(To + (size_t)c * 128);
        a0 += bf2f_lo(v.x); a1 += bf2f_hi(v.x);
        a2 += bf2f_lo(v.y); a3 += bf2f_hi(v.y);
    }
    a0 += __shfl_xor(a0, 32, 64);
    a1 += __shfl_xor(a1, 32, 64);
    a2 += __shfl_xor(a2, 32, 64);
    a3 += __shfl_xor(a3, 32, 64);
    if (half == 0) {
        float inv = invdeg[wid];
        float4 r = *(const float4*)(R + (size_t)wid * 128 + sub * 4);
        float4 o;
        o.x = a0 * inv + r.x;
        o.y = a1 * inv + r.y;
        o.z = a2 * inv + r.z;
        o.w = a3 * inv + r.w;
        *(float4*)(out + (size_t)wid * 128 + sub * 4) = o;
    }
}

// ================= register-streaming MFMA GEMM (barrier-free) =================
// Tailored to tiny-K / huge-M: one wave owns a 16-row strip of A, keeps the full
// A-strip in VGPRs (K<=512 -> <=64 VGPRs), and streams B fragments directly from
// global (weights are <=0.5 MB -> L1/L2-resident, shared by all waves on the CU).
// No LDS, no __syncthreads, 8 independent accumulator chains per k-step.
// KSTEPS = K/32; NGROUPS = Ncols/128.
// SPLIT=0: all cols -> bf16 C0 (ldc0), bias added.
// SPLIT=1: cols 0-127 -> bf16 C0 (ldc 128, no bias); cols 128-255 -> fp32 C1 (ldc 128, +bias).
template <int KSTEPS, int NGROUPS, int SPLIT>
__global__ __launch_bounds__(256) void gemm_rs(const unsigned short* __restrict__ A, int lda,
                                               const unsigned short* __restrict__ B, int ldb,
                                               const float* __restrict__ bias,
                                               unsigned short* __restrict__ C0, int ldc0,
                                               float* __restrict__ C1, int M) {
    int t = threadIdx.x;
    int lane = t & 63;
    int w = t >> 6;
    int row0 = blockIdx.x * 64 + w * 16;   // wave's first row
    int m16 = lane & 15;
    int kq = lane >> 4;                    // k-quad 0..3
    int arow = row0 + m16;
    if (arow > M - 1) arow = M - 1;        // clamp; OOB rows masked at store

    // A-strip resident in registers: frag layout A[m=lane&15][k=kq*8+j]
    const unsigned short* Ap = A + (size_t)arow * lda + kq * 8;
    bf16x8 a[KSTEPS];
#pragma unroll
    for (int ks = 0; ks < KSTEPS; ks++) a[ks] = *(const bf16x8*)(Ap + ks * 32);

    int crow = kq * 4;  // C row base within tile: row = crow + r
#pragma unroll
    for (int g = 0; g < NGROUPS; g++) {
        int n0 = g * 128;
        floatx4 acc[8];
#pragma unroll
        for (int nt = 0; nt < 8; nt++) acc[nt] = (floatx4){0.f, 0.f, 0.f, 0.f};
#pragma unroll
        for (int ks = 0; ks < KSTEPS; ks++) {
#pragma unroll
            for (int nt = 0; nt < 8; nt++) {
                bf16x8 b = *(const bf16x8*)(B + (size_t)(n0 + nt * 16 + m16) * ldb + ks * 32 + kq * 8);
                acc[nt] = __builtin_amdgcn_mfma_f32_16x16x32_bf16(a[ks], b, acc[nt], 0, 0, 0);
            }
        }
        if (SPLIT == 0 || g == 0) {
            int ldc = (SPLIT == 0) ? ldc0 : 128;
            int nc0 = (SPLIT == 0) ? n0 : 0;
#pragma unroll
            for (int nt = 0; nt < 8; nt++) {
                float bv = (SPLIT == 0) ? bias[n0 + nt * 16 + m16] : 0.f;
#pragma unroll
                for (int r = 0; r < 4; r++) {
                    int grow = row0 + crow + r;
                    if (grow < M)
                        C0[(size_t)grow * ldc + nc0 + nt * 16 + m16] = f2bf(acc[nt][r] + bv);
                }
            }
        } else {
            // SPLIT group 1 -> fp32 + bias (bias indexed by r3 column)
#pragma unroll
            for (int nt = 0; nt < 8; nt++) {
                float bv = bias[nt * 16 + m16];
#pragma unroll
                for (int r = 0; r < 4; r++) {
                    int grow = row0 + crow + r;
                    if (grow < M)
                        C1[(size_t)grow * 128 + nt * 16 + m16] = acc[nt][r] + bv;
                }
            }
        }
    }
}

// ================= LayerNorm(256)+ReLU+add, all-bf16 I/O =================
__global__ __launch_bounds__(256) void ln_fuse2(const unsigned short* __restrict__ u, int ustride,
                                                const unsigned short* __restrict__ a, int astride,
                                                const float* __restrict__ g, const float* __restrict__ b,
                                                unsigned short* __restrict__ out, int ostride, int N) {
    int row = (blockIdx.x * blockDim.x + threadIdx.x) >> 6;
    int lane = threadIdx.x & 63;
    if (row >= N) return;
    uint2 uv = *(const uint2*)(u + (size_t)row * ustride + lane * 4);
    float v0 = bf2f_lo(uv.x), v1 = bf2f_hi(uv.x), v2 = bf2f_lo(uv.y), v3 = bf2f_hi(uv.y);
    float s = (v0 + v1) + (v2 + v3);
    float sq = (v0 * v0 + v1 * v1) + (v2 * v2 + v3 * v3);
    for (int off = 1; off < 64; off <<= 1) {
        s += __shfl_xor(s, off, 64);
        sq += __shfl_xor(sq, off, 64);
    }
    float mu = s * (1.f / 256.f);
    float var = sq * (1.f / 256.f) - mu * mu;
    float rs = rsqrtf(var + 1e-5f);
    float4 gv = *(const float4*)(g + lane * 4);
    float4 bv = *(const float4*)(b + lane * 4);
    uint2 av = *(const uint2*)(a + (size_t)row * astride + lane * 4);
    float a0 = bf2f_lo(av.x), a1 = bf2f_hi(av.x), a2 = bf2f_lo(av.y), a3 = bf2f_hi(av.y);
    ushort4 o;
    o.x = f2bf(fmaxf((v0 - mu) * rs * gv.x + bv.x, 0.f) + a0);
    o.y = f2bf(fmaxf((v1 - mu) * rs * gv.y + bv.y, 0.f) + a1);
    o.z = f2bf(fmaxf((v2 - mu) * rs * gv.z + bv.z, 0.f) + a2);
    o.w = f2bf(fmaxf((v3 - mu) * rs * gv.w + bv.w, 0.f) + a3);
    *(ushort4*)(out + (size_t)row * ostride + lane * 4) = o;
}

// ================= launch =================
extern "C" void kernel_launch(void* const* d_in, const int* in_sizes, int n_in,
                              void* d_out, int out_size, void* d_ws, size_t ws_size,
                              hipStream_t stream) {
    const float* x   = (const float*)d_in[0];
    const int*   ei  = (const int*)d_in[1];
    const float* W1l = (const float*)d_in[2];
    const float* b1l = (const float*)d_in[3];
    const float* W1r = (const float*)d_in[4];
    const float* g1  = (const float*)d_in[5];
    const float* be1 = (const float*)d_in[6];
    const float* Wsk = (const float*)d_in[7];
    const float* bsk = (const float*)d_in[8];
    const float* W2l = (const float*)d_in[9];
    const float* b2l = (const float*)d_in[10];
    const float* W2r = (const float*)d_in[11];
    const float* g2  = (const float*)d_in[12];
    const float* be2 = (const float*)d_in[13];
    const float* W3l = (const float*)d_in[14];
    const float* b3l = (const float*)d_in[15];
    const float* W3r = (const float*)d_in[16];

    const int N = in_sizes[0] / 128;
    const int E = in_sizes[1] / 2;
    const int* src = ei;
    const int* dst = ei + E;

    char* p = (char*)d_ws;
    auto alloc = [&](size_t bytes) {
        void* r = (void*)p;
        p += (bytes + 255) & ~(size_t)255;
        return r;
    };
    int*   cnt    = (int*)alloc(sizeof(int) * N);
    int*   rowptr = (int*)alloc(sizeof(int) * (N + 1));
    int*   cursor = (int*)alloc(sizeof(int) * N);
    float* invdeg = (float*)alloc(sizeof(float) * N);
    int*   col    = (int*)alloc(sizeof(int) * E);
    int*   bsum   = (int*)alloc(sizeof(int) * 256);
    int*   boff   = (int*)alloc(sizeof(int) * 256);
    unsigned short* A1cat = (unsigned short*)alloc(sizeof(short) * (size_t)N * 256);  // [agg1|x]; later t3
    unsigned short* A2cat = (unsigned short*)alloc(sizeof(short) * (size_t)N * 512);  // [agg2|h] -> [h2|h]
    unsigned short* U1    = (unsigned short*)alloc(sizeof(short) * (size_t)N * 512);  // [u1|s] bf16; later u2
    float* r3 = (float*)alloc(sizeof(float) * (size_t)N * 128);
    unsigned short* WtC = (unsigned short*)alloc(sizeof(short) * 512 * 256);
    unsigned short* Wt2 = (unsigned short*)alloc(sizeof(short) * 256 * 512);
    unsigned short* Wt3 = (unsigned short*)alloc(sizeof(short) * 256 * 256);
    float* biasC = (float*)alloc(sizeof(float) * 512);
    unsigned short* t3 = A1cat;
    unsigned short* u2 = U1;

    // ---- CSR build ----
    hipMemsetAsync(cnt, 0, sizeof(int) * N, stream);
    hist_kernel<<<(E + 255) / 256, 256, 0, stream>>>(dst, cnt, E);
    int NB = (N + SCAN_CHUNK - 1) / SCAN_CHUNK;
    scan_blocksums<<<NB, 256, 0, stream>>>(cnt, bsum, N);
    scan_bsums<<<1, 256, 0, stream>>>(bsum, boff, NB, rowptr, N, E);
    scan_final<<<NB, 256, 0, stream>>>(cnt, boff, rowptr, cursor, invdeg, N);
    scatter_kernel<<<(E + 255) / 256, 256, 0, stream>>>(src, dst, cursor, col, E);

    // ---- prep ----
    prep_weights<<<(328192 + 255) / 256, 256, 0, stream>>>(W1l, W1r, Wsk, W2l, W2r, W3l, W3r,
                                                           b1l, bsk, WtC, Wt2, Wt3, biasC);
    cvt_x_kernel<<<((N * 128) + 255) / 256, 256, 0, stream>>>(x, A1cat, N * 128);

    int aggBlocks = (N + 3) / 4;
    int gBlocks = (N + 63) / 64;   // register-streaming GEMM: 64 rows/block

    // ---- layer 1 ----
    agg_bf16_v2<<<dim3(aggBlocks, 1), 256, 0, stream>>>(rowptr, col, invdeg, A1cat + 128, 256, A1cat, 256, N);
    // [u1|s] = A1cat @ WtC^T + [b1l|bsk]  (K=256 -> KSTEPS=8, N=512 -> NGROUPS=4)
    gemm_rs<8, 4, 0><<<gBlocks, 256, 0, stream>>>(A1cat, 256, WtC, 256, biasC, U1, 512, nullptr, N);
    // h = relu(LN(u1)) + s -> A2cat right half
    ln_fuse2<<<aggBlocks, 256, 0, stream>>>(U1, 512, U1 + 256, 512, g1, be1, A2cat + 256, 512, N);

    // ---- layer 2 ----
    agg_bf16_v2<<<dim3(aggBlocks, 2), 256, 0, stream>>>(rowptr, col, invdeg, A2cat + 256, 512, A2cat, 512, N);
    // u2 = A2cat @ Wt2^T + b2l  (K=512 -> KSTEPS=16, N=256 -> NGROUPS=2)
    gemm_rs<16, 2, 0><<<gBlocks, 256, 0, stream>>>(A2cat, 512, Wt2, 512, b2l, u2, 256, nullptr, N);
    // h2 = relu(LN(u2)) + h -> A2cat left half
    ln_fuse2<<<aggBlocks, 256, 0, stream>>>(u2, 256, A2cat + 256, 512, g2, be2, A2cat, 512, N);

    // ---- layer 3: split GEMM -> t3 (bf16) + r3 (fp32+bias) ----
    // h2 is A2cat left half (stride 512), K=256 -> KSTEPS=8, N=256 -> NGROUPS=2
    gemm_rs<8, 2, 1><<<gBlocks, 256, 0, stream>>>(A2cat, 512, Wt3, 256, b3l, t3, 128, r3, N);
    agg_final_v2<<<aggBlocks, 256, 0, stream>>>(rowptr, col, invdeg, t3, r3, (float*)d_out, N);
}

// Round 7
// 420.773 us; speedup vs baseline: 1.6699x; 1.6699x over previous
//
#include <hip/hip_runtime.h>

// ---------------- problem dims (fixed by reference) ----------------
// N=50000, E=640000, DIN=128, DH=256, DOUT=128

typedef float floatx4 __attribute__((ext_vector_type(4)));
typedef short bf16x8 __attribute__((ext_vector_type(8)));

__device__ inline unsigned short f2bf(float f) {
    unsigned u = __float_as_uint(f);
    unsigned r = (u + 0x7fffu + ((u >> 16) & 1u)) >> 16;  // RNE
    return (unsigned short)r;
}
__device__ inline float bf2f_lo(unsigned v) { return __uint_as_float(v << 16); }
__device__ inline float bf2f_hi(unsigned v) { return __uint_as_float(v & 0xffff0000u); }

__device__ inline void gl_lds16(const void* g, void* l) {
    __builtin_amdgcn_global_load_lds((const __attribute__((address_space(1))) unsigned int*)g,
                                     (__attribute__((address_space(3))) unsigned int*)l,
                                     16, 0, 0);
}

// ================= CSR build =================
__global__ void hist_kernel(const int* __restrict__ dst, int* __restrict__ cnt, int E) {
    int i = blockIdx.x * blockDim.x + threadIdx.x;
    if (i < E) atomicAdd(&cnt[dst[i]], 1);
}

#define SCAN_CHUNK 2048

__global__ __launch_bounds__(256) void scan_blocksums(const int* __restrict__ cnt,
                                                      int* __restrict__ bsum, int N) {
    __shared__ int sh[256];
    int t = threadIdx.x;
    int base = blockIdx.x * SCAN_CHUNK + t * 8;
    int s = 0;
#pragma unroll
    for (int i = 0; i < 8; i++) {
        int idx = base + i;
        if (idx < N) s += cnt[idx];
    }
    sh[t] = s;
    __syncthreads();
    for (int off = 1; off < 256; off <<= 1) {
        int v = (t >= off) ? sh[t - off] : 0;
        __syncthreads();
        sh[t] += v;
        __syncthreads();
    }
    if (t == 255) bsum[blockIdx.x] = sh[255];
}

__global__ __launch_bounds__(256) void scan_bsums(const int* __restrict__ bsum,
                                                  int* __restrict__ boff, int NB,
                                                  int* __restrict__ rowptr, int N, int E) {
    __shared__ int sh[256];
    int t = threadIdx.x;
    int v = (t < NB) ? bsum[t] : 0;
    sh[t] = v;
    __syncthreads();
    for (int off = 1; off < 256; off <<= 1) {
        int u = (t >= off) ? sh[t - off] : 0;
        __syncthreads();
        sh[t] += u;
        __syncthreads();
    }
    if (t < NB) boff[t] = sh[t] - v;
    if (t == 0) rowptr[N] = E;
}

__global__ __launch_bounds__(256) void scan_final(const int* __restrict__ cnt,
                                                  const int* __restrict__ boff,
                                                  int* __restrict__ rowptr,
                                                  int* __restrict__ cursor,
                                                  float* __restrict__ invdeg, int N) {
    __shared__ int sh[256];
    int t = threadIdx.x;
    int base = blockIdx.x * SCAN_CHUNK + t * 8;
    int c[8];
    int s = 0;
#pragma unroll
    for (int i = 0; i < 8; i++) {
        int idx = base + i;
        c[i] = (idx < N) ? cnt[idx] : 0;
        s += c[i];
    }
    sh[t] = s;
    __syncthreads();
    for (int off = 1; off < 256; off <<= 1) {
        int v = (t >= off) ? sh[t - off] : 0;
        __syncthreads();
        sh[t] += v;
        __syncthreads();
    }
    int run = boff[blockIdx.x] + sh[t] - s;
#pragma unroll
    for (int i = 0; i < 8; i++) {
        int idx = base + i;
        if (idx < N) {
            rowptr[idx] = run;
            cursor[idx] = run;
            invdeg[idx] = 1.0f / (float)(c[i] > 1 ? c[i] : 1);
            run += c[i];
        }
    }
}

__global__ void scatter_kernel(const int* __restrict__ src, const int* __restrict__ dst,
                               int* __restrict__ cursor, int* __restrict__ col, int E) {
    int i = blockIdx.x * blockDim.x + threadIdx.x;
    if (i < E) {
        int p = atomicAdd(&cursor[dst[i]], 1);
        col[p] = src[i];
    }
}

// ================= fused weight prep =================
// WtC [512,256]: rows 0-255 = [W1l;W1r]^T (u), rows 256-511 = [0;Wsk]^T (s)
// Wt2 [256,512]  ;  Wt3 [256,256]: rows 0-127 W3l^T, 128-255 W3r^T
// biasC [512] = [b1l | bsk]
__global__ void prep_weights(const float* __restrict__ W1l, const float* __restrict__ W1r,
                             const float* __restrict__ Wsk, const float* __restrict__ W2l,
                             const float* __restrict__ W2r, const float* __restrict__ W3l,
                             const float* __restrict__ W3r, const float* __restrict__ b1l,
                             const float* __restrict__ bsk,
                             unsigned short* __restrict__ WtC, unsigned short* __restrict__ Wt2,
                             unsigned short* __restrict__ Wt3, float* __restrict__ biasC) {
    int i = blockIdx.x * blockDim.x + threadIdx.x;
    if (i < 32768) {                        // W1l [128,256]
        int k = i >> 8, n = i & 255;
        WtC[n * 256 + k] = f2bf(W1l[i]);
    } else if (i < 65536) {                 // W1r
        int j = i - 32768, k = j >> 8, n = j & 255;
        WtC[n * 256 + 128 + k] = f2bf(W1r[j]);
    } else if (i < 98304) {                 // Wsk -> rows 256-511, k-half 128-255
        int j = i - 65536, k = j >> 8, n = j & 255;
        WtC[(256 + n) * 256 + 128 + k] = f2bf(Wsk[j]);
    } else if (i < 131072) {                // zero-fill rows 256-511, k-half 0-127
        int j = i - 98304, k = j >> 8, n = j & 255;
        WtC[(256 + n) * 256 + k] = 0;
    } else if (i < 196608) {                // W2l [256,256]
        int j = i - 131072, k = j >> 8, n = j & 255;
        Wt2[n * 512 + k] = f2bf(W2l[j]);
    } else if (i < 262144) {                // W2r
        int j = i - 196608, k = j >> 8, n = j & 255;
        Wt2[n * 512 + 256 + k] = f2bf(W2r[j]);
    } else if (i < 294912) {                // W3l [256,128]
        int j = i - 262144, k = j >> 7, n = j & 127;
        Wt3[n * 256 + k] = f2bf(W3l[j]);
    } else if (i < 327680) {                // W3r
        int j = i - 294912, k = j >> 7, n = j & 127;
        Wt3[(128 + n) * 256 + k] = f2bf(W3r[j]);
    } else if (i < 328192) {                // biasC [512]
        int j = i - 327680;
        biasC[j] = (j < 256) ? b1l[j] : bsk[j - 256];
    }
}

__global__ void cvt_x_kernel(const float* __restrict__ x, unsigned short* __restrict__ A1cat, int total) {
    int i = blockIdx.x * blockDim.x + threadIdx.x;
    if (i >= total) return;
    int r = i >> 7, c = i & 127;
    A1cat[(size_t)r * 256 + 128 + c] = f2bf(x[i]);
}

// ================= CSR mean aggregation v2 =================
__global__ __launch_bounds__(256) void agg_bf16_v2(const int* __restrict__ rowptr,
                                                   const int* __restrict__ col,
                                                   const float* __restrict__ invdeg,
                                                   const unsigned short* __restrict__ X, int xstride,
                                                   unsigned short* __restrict__ out, int ostride, int N) {
    int wid = (blockIdx.x * blockDim.x + threadIdx.x) >> 6;
    int lane = threadIdx.x & 63;
    if (wid >= N) return;
    int half = lane >> 5;
    int sub = lane & 31;
    int off = blockIdx.y * 128 + sub * 4;
    const unsigned short* Xo = X + off;
    int s = rowptr[wid], e = rowptr[wid + 1];
    float a0 = 0.f, a1 = 0.f, a2 = 0.f, a3 = 0.f;
    int j = s + half;
    for (; j + 6 < e; j += 8) {
        int c0 = col[j], c1 = col[j + 2], c2 = col[j + 4], c3 = col[j + 6];
        uint2 v0 = *(const uint2*)(Xo + (size_t)c0 * xstride);
        uint2 v1 = *(const uint2*)(Xo + (size_t)c1 * xstride);
        uint2 v2 = *(const uint2*)(Xo + (size_t)c2 * xstride);
        uint2 v3 = *(const uint2*)(Xo + (size_t)c3 * xstride);
        a0 += (bf2f_lo(v0.x) + bf2f_lo(v1.x)) + (bf2f_lo(v2.x) + bf2f_lo(v3.x));
        a1 += (bf2f_hi(v0.x) + bf2f_hi(v1.x)) + (bf2f_hi(v2.x) + bf2f_hi(v3.x));
        a2 += (bf2f_lo(v0.y) + bf2f_lo(v1.y)) + (bf2f_lo(v2.y) + bf2f_lo(v3.y));
        a3 += (bf2f_hi(v0.y) + bf2f_hi(v1.y)) + (bf2f_hi(v2.y) + bf2f_hi(v3.y));
    }
    for (; j < e; j += 2) {
        int c = col[j];
        uint2 v = *(const uint2*)(Xo + (size_t)c * xstride);
        a0 += bf2f_lo(v.x); a1 += bf2f_hi(v.x);
        a2 += bf2f_lo(v.y); a3 += bf2f_hi(v.y);
    }
    a0 += __shfl_xor(a0, 32, 64);
    a1 += __shfl_xor(a1, 32, 64);
    a2 += __shfl_xor(a2, 32, 64);
    a3 += __shfl_xor(a3, 32, 64);
    if (half == 0) {
        float inv = invdeg[wid];
        ushort4 o;
        o.x = f2bf(a0 * inv); o.y = f2bf(a1 * inv);
        o.z = f2bf(a2 * inv); o.w = f2bf(a3 * inv);
        *(ushort4*)(out + (size_t)wid * ostride + off) = o;
    }
}

// final: out = mean-agg(T bf16 [N,128]) + R fp32 [N,128], fp32 out
__global__ __launch_bounds__(256) void agg_final_v2(const int* __restrict__ rowptr,
                                                    const int* __restrict__ col,
                                                    const float* __restrict__ invdeg,
                                                    const unsigned short* __restrict__ T,
                                                    const float* __restrict__ R,
                                                    float* __restrict__ out, int N) {
    int wid = (blockIdx.x * blockDim.x + threadIdx.x) >> 6;
    int lane = threadIdx.x & 63;
    if (wid >= N) return;
    int half = lane >> 5;
    int sub = lane & 31;
    const unsigned short* To = T + sub * 4;
    int s = rowptr[wid], e = rowptr[wid + 1];
    float a0 = 0.f, a1 = 0.f, a2 = 0.f, a3 = 0.f;
    int j = s + half;
    for (; j + 6 < e; j += 8) {
        int c0 = col[j], c1 = col[j + 2], c2 = col[j + 4], c3 = col[j + 6];
        uint2 v0 = *(const uint2*)(To + (size_t)c0 * 128);
        uint2 v1 = *(const uint2*)(To + (size_t)c1 * 128);
        uint2 v2 = *(const uint2*)(To + (size_t)c2 * 128);
        uint2 v3 = *(const uint2*)(To + (size_t)c3 * 128);
        a0 += (bf2f_lo(v0.x) + bf2f_lo(v1.x)) + (bf2f_lo(v2.x) + bf2f_lo(v3.x));
        a1 += (bf2f_hi(v0.x) + bf2f_hi(v1.x)) + (bf2f_hi(v2.x) + bf2f_hi(v3.x));
        a2 += (bf2f_lo(v0.y) + bf2f_lo(v1.y)) + (bf2f_lo(v2.y) + bf2f_lo(v3.y));
        a3 += (bf2f_hi(v0.y) + bf2f_hi(v1.y)) + (bf2f_hi(v2.y) + bf2f_hi(v3.y));
    }
    for (; j < e; j += 2) {
        int c = col[j];
        uint2 v = *(const uint2*)(To + (size_t)c * 128);
        a0 += bf2f_lo(v.x); a1 += bf2f_hi(v.x);
        a2 += bf2f_lo(v.y); a3 += bf2f_hi(v.y);
    }
    a0 += __shfl_xor(a0, 32, 64);
    a1 += __shfl_xor(a1, 32, 64);
    a2 += __shfl_xor(a2, 32, 64);
    a3 += __shfl_xor(a3, 32, 64);
    if (half == 0) {
        float inv = invdeg[wid];
        float4 r = *(const float4*)(R + (size_t)wid * 128 + sub * 4);
        float4 o;
        o.x = a0 * inv + r.x;
        o.y = a1 * inv + r.y;
        o.z = a2 * inv + r.z;
        o.w = a3 * inv + r.w;
        *(float4*)(out + (size_t)wid * 128 + sub * 4) = o;
    }
}

// ================= bf16 MFMA GEMM, XOR-swizzled LDS + bounce epilogue =================
// A bf16 [M,K] (lda), B=W^T bf16 [Ncols,K] (ldb). 128x128 tile, BK=64, 4 waves 2x2.
// LDS swizzle: physical 16B-chunk pc = logical kc ^ (row&7), realized by permuting the
// GLOBAL SOURCE of global_load_lds (dest must stay lane-linear). Fragment reads then
// hit all 32 banks 2-way (free) instead of 16-way.
// Epilogue: acc -> per-wave LDS pad-34 fp32 buffer (wave-in-order DS, no barrier) ->
// fully coalesced 16B/lane stores with bias folded in.
// SPLIT=0: all cols -> bf16 C0(ldc0) + bias.  SPLIT=1: grid.y=2; bn=0 -> bf16 C0(ldc 128,
// no bias), bn=128 -> fp32 C1(ldc 128, +bias).
template <int KIT, int SPLIT>
__global__ __launch_bounds__(256) void gemm_lds(const unsigned short* __restrict__ A, int lda,
                                                const unsigned short* __restrict__ B, int ldb,
                                                const float* __restrict__ bias,
                                                unsigned short* __restrict__ C0, int ldc0,
                                                float* __restrict__ C1, int M) {
    __shared__ __align__(16) char smem[34816];  // max(staging 32KB, bounce 4*64*34*4)
    unsigned short* sA = (unsigned short*)smem;      // [128 rows][8 chunks][8 elems]
    unsigned short* sB = sA + 128 * 64;
    int t = threadIdx.x;
    int lane = t & 63, w = t >> 6;
    int bm = blockIdx.x * 128, bn = blockIdx.y * 128;
    int wm = (w >> 1) * 64, wn = (w & 1) * 64;
    int m16 = lane & 15, kq = lane >> 4;

    floatx4 acc[4][4];
#pragma unroll
    for (int i = 0; i < 4; i++)
#pragma unroll
        for (int j = 0; j < 4; j++) acc[i][j] = (floatx4){0.f, 0.f, 0.f, 0.f};

    const int c_row = t >> 3;                  // staging row (mod 32)
    const int kc = (t & 7) ^ (c_row & 7);      // logical k-chunk for this thread's slot
    const int srcOff = kc * 8;
    const int fsw = (m16 & 7);                 // fragment-read swizzle key

    for (int kt = 0; kt < KIT; kt++) {
        int k0 = kt * 64;
#pragma unroll
        for (int i = 0; i < 4; i++) {
            int rowA = bm + i * 32 + c_row;
            if (rowA > M - 1) rowA = M - 1;    // clamp; output rows masked at store
            gl_lds16(A + (size_t)rowA * lda + k0 + srcOff, (void*)&sA[(size_t)(i * 256 + t) * 8]);
            gl_lds16(B + (size_t)(bn + i * 32 + c_row) * ldb + k0 + srcOff,
                     (void*)&sB[(size_t)(i * 256 + t) * 8]);
        }
        __syncthreads();
#pragma unroll
        for (int ks = 0; ks < 2; ks++) {
            int kcl = (ks << 2) | kq;
            bf16x8 af[4], bfr[4];
#pragma unroll
            for (int mi = 0; mi < 4; mi++)
                af[mi] = *(const bf16x8*)&sA[(wm + mi * 16 + m16) * 64 + (kcl ^ fsw) * 8];
#pragma unroll
            for (int ni = 0; ni < 4; ni++)
                bfr[ni] = *(const bf16x8*)&sB[(wn + ni * 16 + m16) * 64 + (kcl ^ fsw) * 8];
#pragma unroll
            for (int mi = 0; mi < 4; mi++)
#pragma unroll
                for (int ni = 0; ni < 4; ni++)
                    acc[mi][ni] = __builtin_amdgcn_mfma_f32_16x16x32_bf16(af[mi], bfr[ni], acc[mi][ni], 0, 0, 0);
        }
        __syncthreads();
    }

    // ---- bounce epilogue: 2 halves of 32 cols through per-wave LDS ----
    float* wb = (float*)smem + w * (64 * 34);
    const float* bias0 = (SPLIT == 0) ? bias : ((bn == 0) ? nullptr : bias);
#pragma unroll
    for (int h = 0; h < 2; h++) {
#pragma unroll
        for (int nj = 0; nj < 2; nj++) {
            int ni = h * 2 + nj;
#pragma unroll
            for (int mi = 0; mi < 4; mi++)
#pragma unroll
                for (int r = 0; r < 4; r++)
                    wb[(mi * 16 + kq * 4 + r) * 34 + nj * 16 + m16] = acc[mi][ni][r];
        }
        asm volatile("s_waitcnt lgkmcnt(0)" ::: "memory");
        if (SPLIT == 0 || bn == 0) {
            // bf16 output, optional bias
            int rsub = lane >> 2, c8 = (lane & 3) * 8;
            int ldc = (SPLIT == 0) ? ldc0 : 128;
            int gcol = ((SPLIT == 0) ? bn : 0) + wn + h * 32 + c8;
            float bv[8];
#pragma unroll
            for (int j = 0; j < 8; j++) bv[j] = bias0 ? bias0[gcol + j] : 0.f;
#pragma unroll
            for (int it = 0; it < 4; it++) {
                int rr = it * 16 + rsub;
                int grow = bm + wm + rr;
                float v0 = wb[rr * 34 + c8 + 0] + bv[0];
                float v1 = wb[rr * 34 + c8 + 1] + bv[1];
                float v2 = wb[rr * 34 + c8 + 2] + bv[2];
                float v3 = wb[rr * 34 + c8 + 3] + bv[3];
                float v4 = wb[rr * 34 + c8 + 4] + bv[4];
                float v5 = wb[rr * 34 + c8 + 5] + bv[5];
                float v6 = wb[rr * 34 + c8 + 6] + bv[6];
                float v7 = wb[rr * 34 + c8 + 7] + bv[7];
                uint4 o;
                o.x = (unsigned)f2bf(v0) | ((unsigned)f2bf(v1) << 16);
                o.y = (unsigned)f2bf(v2) | ((unsigned)f2bf(v3) << 16);
                o.z = (unsigned)f2bf(v4) | ((unsigned)f2bf(v5) << 16);
                o.w = (unsigned)f2bf(v6) | ((unsigned)f2bf(v7) << 16);
                if (grow < M) *(uint4*)(C0 + (size_t)grow * ldc + gcol) = o;
            }
        } else {
            // fp32 output + bias (r3); bn==128 -> r3 col = wn + h*32 + ...
            int rsub = lane >> 3, c4 = (lane & 7) * 4;
            int gcol = wn + h * 32 + c4;
            float bv[4];
#pragma unroll
            for (int j = 0; j < 4; j++) bv[j] = bias0[gcol + j];
#pragma unroll
            for (int it = 0; it < 8; it++) {
                int rr = it * 8 + rsub;
                int grow = bm + wm + rr;
                float4 o;
                o.x = wb[rr * 34 + c4 + 0] + bv[0];
                o.y = wb[rr * 34 + c4 + 1] + bv[1];
                o.z = wb[rr * 34 + c4 + 2] + bv[2];
                o.w = wb[rr * 34 + c4 + 3] + bv[3];
                if (grow < M) *(float4*)(C1 + (size_t)grow * 128 + gcol) = o;
            }
        }
        if (h == 0) asm volatile("s_waitcnt lgkmcnt(0)" ::: "memory");
    }
}

// ================= LayerNorm(256)+ReLU+add, all-bf16 I/O =================
__global__ __launch_bounds__(256) void ln_fuse2(const unsigned short* __restrict__ u, int ustride,
                                                const unsigned short* __restrict__ a, int astride,
                                                const float* __restrict__ g, const float* __restrict__ b,
                                                unsigned short* __restrict__ out, int ostride, int N) {
    int row = (blockIdx.x * blockDim.x + threadIdx.x) >> 6;
    int lane = threadIdx.x & 63;
    if (row >= N) return;
    uint2 uv = *(const uint2*)(u + (size_t)row * ustride + lane * 4);
    float v0 = bf2f_lo(uv.x), v1 = bf2f_hi(uv.x), v2 = bf2f_lo(uv.y), v3 = bf2f_hi(uv.y);
    float s = (v0 + v1) + (v2 + v3);
    float sq = (v0 * v0 + v1 * v1) + (v2 * v2 + v3 * v3);
    for (int off = 1; off < 64; off <<= 1) {
        s += __shfl_xor(s, off, 64);
        sq += __shfl_xor(sq, off, 64);
    }
    float mu = s * (1.f / 256.f);
    float var = sq * (1.f / 256.f) - mu * mu;
    float rs = rsqrtf(var + 1e-5f);
    float4 gv = *(const float4*)(g + lane * 4);
    float4 bv = *(const float4*)(b + lane * 4);
    uint2 av = *(const uint2*)(a + (size_t)row * astride + lane * 4);
    float a0 = bf2f_lo(av.x), a1 = bf2f_hi(av.x), a2 = bf2f_lo(av.y), a3 = bf2f_hi(av.y);
    ushort4 o;
    o.x = f2bf(fmaxf((v0 - mu) * rs * gv.x + bv.x, 0.f) + a0);
    o.y = f2bf(fmaxf((v1 - mu) * rs * gv.y + bv.y, 0.f) + a1);
    o.z = f2bf(fmaxf((v2 - mu) * rs * gv.z + bv.z, 0.f) + a2);
    o.w = f2bf(fmaxf((v3 - mu) * rs * gv.w + bv.w, 0.f) + a3);
    *(ushort4*)(out + (size_t)row * ostride + lane * 4) = o;
}

// ================= launch =================
extern "C" void kernel_launch(void* const* d_in, const int* in_sizes, int n_in,
                              void* d_out, int out_size, void* d_ws, size_t ws_size,
                              hipStream_t stream) {
    const float* x   = (const float*)d_in[0];
    const int*   ei  = (const int*)d_in[1];
    const float* W1l = (const float*)d_in[2];
    const float* b1l = (const float*)d_in[3];
    const float* W1r = (const float*)d_in[4];
    const float* g1  = (const float*)d_in[5];
    const float* be1 = (const float*)d_in[6];
    const float* Wsk = (const float*)d_in[7];
    const float* bsk = (const float*)d_in[8];
    const float* W2l = (const float*)d_in[9];
    const float* b2l = (const float*)d_in[10];
    const float* W2r = (const float*)d_in[11];
    const float* g2  = (const float*)d_in[12];
    const float* be2 = (const float*)d_in[13];
    const float* W3l = (const float*)d_in[14];
    const float* b3l = (const float*)d_in[15];
    const float* W3r = (const float*)d_in[16];

    const int N = in_sizes[0] / 128;
    const int E = in_sizes[1] / 2;
    const int* src = ei;
    const int* dst = ei + E;

    char* p = (char*)d_ws;
    auto alloc = [&](size_t bytes) {
        void* r = (void*)p;
        p += (bytes + 255) & ~(size_t)255;
        return r;
    };
    int*   cnt    = (int*)alloc(sizeof(int) * N);
    int*   rowptr = (int*)alloc(sizeof(int) * (N + 1));
    int*   cursor = (int*)alloc(sizeof(int) * N);
    float* invdeg = (float*)alloc(sizeof(float) * N);
    int*   col    = (int*)alloc(sizeof(int) * E);
    int*   bsum   = (int*)alloc(sizeof(int) * 256);
    int*   boff   = (int*)alloc(sizeof(int) * 256);
    unsigned short* A1cat = (unsigned short*)alloc(sizeof(short) * (size_t)N * 256);  // [agg1|x]; later t3
    unsigned short* A2cat = (unsigned short*)alloc(sizeof(short) * (size_t)N * 512);  // [agg2|h] -> [h2|h]
    unsigned short* U1    = (unsigned short*)alloc(sizeof(short) * (size_t)N * 512);  // [u1|s] bf16; later u2
    float* r3 = (float*)alloc(sizeof(float) * (size_t)N * 128);
    unsigned short* WtC = (unsigned short*)alloc(sizeof(short) * 512 * 256);
    unsigned short* Wt2 = (unsigned short*)alloc(sizeof(short) * 256 * 512);
    unsigned short* Wt3 = (unsigned short*)alloc(sizeof(short) * 256 * 256);
    float* biasC = (float*)alloc(sizeof(float) * 512);
    unsigned short* t3 = A1cat;
    unsigned short* u2 = U1;

    // ---- CSR build ----
    hipMemsetAsync(cnt, 0, sizeof(int) * N, stream);
    hist_kernel<<<(E + 255) / 256, 256, 0, stream>>>(dst, cnt, E);
    int NB = (N + SCAN_CHUNK - 1) / SCAN_CHUNK;
    scan_blocksums<<<NB, 256, 0, stream>>>(cnt, bsum, N);
    scan_bsums<<<1, 256, 0, stream>>>(bsum, boff, NB, rowptr, N, E);
    scan_final<<<NB, 256, 0, stream>>>(cnt, boff, rowptr, cursor, invdeg, N);
    scatter_kernel<<<(E + 255) / 256, 256, 0, stream>>>(src, dst, cursor, col, E);

    // ---- prep ----
    prep_weights<<<(328192 + 255) / 256, 256, 0, stream>>>(W1l, W1r, Wsk, W2l, W2r, W3l, W3r,
                                                           b1l, bsk, WtC, Wt2, Wt3, biasC);
    cvt_x_kernel<<<((N * 128) + 255) / 256, 256, 0, stream>>>(x, A1cat, N * 128);

    int aggBlocks = (N + 3) / 4;
    int mBlocks = (N + 127) / 128;

    // ---- layer 1 ----
    agg_bf16_v2<<<dim3(aggBlocks, 1), 256, 0, stream>>>(rowptr, col, invdeg, A1cat + 128, 256, A1cat, 256, N);
    // [u1|s] = A1cat @ WtC^T + [b1l|bsk]  (K=256 -> KIT=4, 512 cols -> grid.y=4)
    gemm_lds<4, 0><<<dim3(mBlocks, 4), 256, 0, stream>>>(A1cat, 256, WtC, 256, biasC, U1, 512, nullptr, N);
    ln_fuse2<<<aggBlocks, 256, 0, stream>>>(U1, 512, U1 + 256, 512, g1, be1, A2cat + 256, 512, N);

    // ---- layer 2 ----
    agg_bf16_v2<<<dim3(aggBlocks, 2), 256, 0, stream>>>(rowptr, col, invdeg, A2cat + 256, 512, A2cat, 512, N);
    // u2 = A2cat @ Wt2^T + b2l  (K=512 -> KIT=8, 256 cols -> grid.y=2)
    gemm_lds<8, 0><<<dim3(mBlocks, 2), 256, 0, stream>>>(A2cat, 512, Wt2, 512, b2l, u2, 256, nullptr, N);
    ln_fuse2<<<aggBlocks, 256, 0, stream>>>(u2, 256, A2cat + 256, 512, g2, be2, A2cat, 512, N);

    // ---- layer 3: split GEMM -> t3 (bf16) + r3 (fp32+bias) ----
    gemm_lds<4, 1><<<dim3(mBlocks, 2), 256, 0, stream>>>(A2cat, 512, Wt3, 256, b3l, t3, 128, r3, N);
    agg_final_v2<<<aggBlocks, 256, 0, stream>>>(rowptr, col, invdeg, t3, r3, (float*)d_out, N);
}

// Round 8
// 410.370 us; speedup vs baseline: 1.7122x; 1.0254x over previous
//
#include <hip/hip_runtime.h>

// ---------------- problem dims (fixed by reference) ----------------
// N=50000, E=640000, DIN=128, DH=256, DOUT=128

typedef float floatx4 __attribute__((ext_vector_type(4)));
typedef float floatx2 __attribute__((ext_vector_type(2)));
typedef short bf16x8 __attribute__((ext_vector_type(8)));

#if defined(__has_builtin)
#if __has_builtin(__builtin_amdgcn_cvt_pk_f32_fp8) && __has_builtin(__builtin_amdgcn_cvt_pk_fp8_f32)
#define HAS_FP8_CVT 1
#endif
#endif
#ifndef HAS_FP8_CVT
#define HAS_FP8_CVT 0
#endif

__device__ inline unsigned short f2bf(float f) {
    unsigned u = __float_as_uint(f);
    unsigned r = (u + 0x7fffu + ((u >> 16) & 1u)) >> 16;  // RNE
    return (unsigned short)r;
}
__device__ inline float bf2f_lo(unsigned v) { return __uint_as_float(v << 16); }
__device__ inline float bf2f_hi(unsigned v) { return __uint_as_float(v & 0xffff0000u); }

__device__ inline void gl_lds16(const void* g, void* l) {
    __builtin_amdgcn_global_load_lds((const __attribute__((address_space(1))) unsigned int*)g,
                                     (__attribute__((address_space(3))) unsigned int*)l,
                                     16, 0, 0);
}

// ================= CSR build =================
__global__ void hist_kernel(const int* __restrict__ dst, int* __restrict__ cnt, int E) {
    int i = blockIdx.x * blockDim.x + threadIdx.x;
    if (i < E) atomicAdd(&cnt[dst[i]], 1);
}

#define SCAN_CHUNK 2048

__global__ __launch_bounds__(256) void scan_blocksums(const int* __restrict__ cnt,
                                                      int* __restrict__ bsum, int N) {
    __shared__ int sh[256];
    int t = threadIdx.x;
    int base = blockIdx.x * SCAN_CHUNK + t * 8;
    int s = 0;
#pragma unroll
    for (int i = 0; i < 8; i++) {
        int idx = base + i;
        if (idx < N) s += cnt[idx];
    }
    sh[t] = s;
    __syncthreads();
    for (int off = 1; off < 256; off <<= 1) {
        int v = (t >= off) ? sh[t - off] : 0;
        __syncthreads();
        sh[t] += v;
        __syncthreads();
    }
    if (t == 255) bsum[blockIdx.x] = sh[255];
}

__global__ __launch_bounds__(256) void scan_bsums(const int* __restrict__ bsum,
                                                  int* __restrict__ boff, int NB,
                                                  int* __restrict__ rowptr, int N, int E) {
    __shared__ int sh[256];
    int t = threadIdx.x;
    int v = (t < NB) ? bsum[t] : 0;
    sh[t] = v;
    __syncthreads();
    for (int off = 1; off < 256; off <<= 1) {
        int u = (t >= off) ? sh[t - off] : 0;
        __syncthreads();
        sh[t] += u;
        __syncthreads();
    }
    if (t < NB) boff[t] = sh[t] - v;
    if (t == 0) rowptr[N] = E;
}

__global__ __launch_bounds__(256) void scan_final(const int* __restrict__ cnt,
                                                  const int* __restrict__ boff,
                                                  int* __restrict__ rowptr,
                                                  int* __restrict__ cursor,
                                                  float* __restrict__ invdeg, int N) {
    __shared__ int sh[256];
    int t = threadIdx.x;
    int base = blockIdx.x * SCAN_CHUNK + t * 8;
    int c[8];
    int s = 0;
#pragma unroll
    for (int i = 0; i < 8; i++) {
        int idx = base + i;
        c[i] = (idx < N) ? cnt[idx] : 0;
        s += c[i];
    }
    sh[t] = s;
    __syncthreads();
    for (int off = 1; off < 256; off <<= 1) {
        int v = (t >= off) ? sh[t - off] : 0;
        __syncthreads();
        sh[t] += v;
        __syncthreads();
    }
    int run = boff[blockIdx.x] + sh[t] - s;
#pragma unroll
    for (int i = 0; i < 8; i++) {
        int idx = base + i;
        if (idx < N) {
            rowptr[idx] = run;
            cursor[idx] = run;
            invdeg[idx] = 1.0f / (float)(c[i] > 1 ? c[i] : 1);
            run += c[i];
        }
    }
}

__global__ void scatter_kernel(const int* __restrict__ src, const int* __restrict__ dst,
                               int* __restrict__ cursor, int* __restrict__ col, int E) {
    int i = blockIdx.x * blockDim.x + threadIdx.x;
    if (i < E) {
        int p = atomicAdd(&cursor[dst[i]], 1);
        col[p] = src[i];
    }
}

// ================= fused weight prep =================
// WtC [512,256]: rows 0-255 = [W1l;W1r]^T (u), rows 256-511 = [0;Wsk]^T (s)
// Wt2 [256,512]  ;  Wt3 [256,256]: rows 0-127 W3l^T, 128-255 W3r^T
// biasC [512] = [b1l | bsk]
__global__ void prep_weights(const float* __restrict__ W1l, const float* __restrict__ W1r,
                             const float* __restrict__ Wsk, const float* __restrict__ W2l,
                             const float* __restrict__ W2r, const float* __restrict__ W3l,
                             const float* __restrict__ W3r, const float* __restrict__ b1l,
                             const float* __restrict__ bsk,
                             unsigned short* __restrict__ WtC, unsigned short* __restrict__ Wt2,
                             unsigned short* __restrict__ Wt3, float* __restrict__ biasC) {
    int i = blockIdx.x * blockDim.x + threadIdx.x;
    if (i < 32768) {                        // W1l [128,256]
        int k = i >> 8, n = i & 255;
        WtC[n * 256 + k] = f2bf(W1l[i]);
    } else if (i < 65536) {                 // W1r
        int j = i - 32768, k = j >> 8, n = j & 255;
        WtC[n * 256 + 128 + k] = f2bf(W1r[j]);
    } else if (i < 98304) {                 // Wsk -> rows 256-511, k-half 128-255
        int j = i - 65536, k = j >> 8, n = j & 255;
        WtC[(256 + n) * 256 + 128 + k] = f2bf(Wsk[j]);
    } else if (i < 131072) {                // zero-fill rows 256-511, k-half 0-127
        int j = i - 98304, k = j >> 8, n = j & 255;
        WtC[(256 + n) * 256 + k] = 0;
    } else if (i < 196608) {                // W2l [256,256]
        int j = i - 131072, k = j >> 8, n = j & 255;
        Wt2[n * 512 + k] = f2bf(W2l[j]);
    } else if (i < 262144) {                // W2r
        int j = i - 196608, k = j >> 8, n = j & 255;
        Wt2[n * 512 + 256 + k] = f2bf(W2r[j]);
    } else if (i < 294912) {                // W3l [256,128]
        int j = i - 262144, k = j >> 7, n = j & 127;
        Wt3[n * 256 + k] = f2bf(W3l[j]);
    } else if (i < 327680) {                // W3r
        int j = i - 294912, k = j >> 7, n = j & 127;
        Wt3[(128 + n) * 256 + k] = f2bf(W3r[j]);
    } else if (i < 328192) {                // biasC [512]
        int j = i - 327680;
        biasC[j] = (j < 256) ? b1l[j] : bsk[j - 256];
    }
}

__global__ void cvt_x_kernel(const float* __restrict__ x, unsigned short* __restrict__ A1cat, int total) {
    int i = blockIdx.x * blockDim.x + threadIdx.x;
    if (i >= total) return;
    int r = i >> 7, c = i & 127;
    A1cat[(size_t)r * 256 + 128 + c] = f2bf(x[i]);
}

// ================= CSR mean aggregation, predicated unroll x4 =================
// one wave per (node, 128-col slice); lane>>5 = edge parity; always 4 gathers in flight.
__global__ __launch_bounds__(256) void agg_bf16_v3(const int* __restrict__ rowptr,
                                                   const int* __restrict__ col,
                                                   const float* __restrict__ invdeg,
                                                   const unsigned short* __restrict__ X, int xstride,
                                                   unsigned short* __restrict__ out, int ostride, int N) {
    int wid = (blockIdx.x * blockDim.x + threadIdx.x) >> 6;
    int lane = threadIdx.x & 63;
    if (wid >= N) return;
    int half = lane >> 5;
    int sub = lane & 31;
    int off = blockIdx.y * 128 + sub * 4;
    const unsigned short* Xo = X + off;
    int s = rowptr[wid], e = rowptr[wid + 1];
    float a0 = 0.f, a1 = 0.f, a2 = 0.f, a3 = 0.f;
    for (int j = s + half; j < e; j += 8) {
        int j1 = (j + 2 < e) ? j + 2 : j;
        int j2 = (j + 4 < e) ? j + 4 : j;
        int j3 = (j + 6 < e) ? j + 6 : j;
        float m1 = (j + 2 < e) ? 1.f : 0.f;
        float m2 = (j + 4 < e) ? 1.f : 0.f;
        float m3 = (j + 6 < e) ? 1.f : 0.f;
        int c0 = col[j], c1 = col[j1], c2 = col[j2], c3 = col[j3];
        uint2 v0 = *(const uint2*)(Xo + (size_t)c0 * xstride);
        uint2 v1 = *(const uint2*)(Xo + (size_t)c1 * xstride);
        uint2 v2 = *(const uint2*)(Xo + (size_t)c2 * xstride);
        uint2 v3 = *(const uint2*)(Xo + (size_t)c3 * xstride);
        a0 += bf2f_lo(v0.x); a1 += bf2f_hi(v0.x); a2 += bf2f_lo(v0.y); a3 += bf2f_hi(v0.y);
        a0 = fmaf(m1, bf2f_lo(v1.x), a0); a1 = fmaf(m1, bf2f_hi(v1.x), a1);
        a2 = fmaf(m1, bf2f_lo(v1.y), a2); a3 = fmaf(m1, bf2f_hi(v1.y), a3);
        a0 = fmaf(m2, bf2f_lo(v2.x), a0); a1 = fmaf(m2, bf2f_hi(v2.x), a1);
        a2 = fmaf(m2, bf2f_lo(v2.y), a2); a3 = fmaf(m2, bf2f_hi(v2.y), a3);
        a0 = fmaf(m3, bf2f_lo(v3.x), a0); a1 = fmaf(m3, bf2f_hi(v3.x), a1);
        a2 = fmaf(m3, bf2f_lo(v3.y), a2); a3 = fmaf(m3, bf2f_hi(v3.y), a3);
    }
    a0 += __shfl_xor(a0, 32, 64);
    a1 += __shfl_xor(a1, 32, 64);
    a2 += __shfl_xor(a2, 32, 64);
    a3 += __shfl_xor(a3, 32, 64);
    if (half == 0) {
        float inv = invdeg[wid];
        ushort4 o;
        o.x = f2bf(a0 * inv); o.y = f2bf(a1 * inv);
        o.z = f2bf(a2 * inv); o.w = f2bf(a3 * inv);
        *(ushort4*)(out + (size_t)wid * ostride + off) = o;
    }
}

#if HAS_FP8_CVT
// layer-2 agg over fp8 h-table [N,256] (1B/col, 256B rows). One wave covers the full
// row: 32 lanes x 8B; lane>>5 = edge parity; predicated unroll x4 -> 4 gathers in flight.
__device__ inline void accum_fp8(uint2 v, float m, float* a) {
    floatx2 p;
    p = __builtin_amdgcn_cvt_pk_f32_fp8(v.x, false); a[0] = fmaf(m, p.x, a[0]); a[1] = fmaf(m, p.y, a[1]);
    p = __builtin_amdgcn_cvt_pk_f32_fp8(v.x, true);  a[2] = fmaf(m, p.x, a[2]); a[3] = fmaf(m, p.y, a[3]);
    p = __builtin_amdgcn_cvt_pk_f32_fp8(v.y, false); a[4] = fmaf(m, p.x, a[4]); a[5] = fmaf(m, p.y, a[5]);
    p = __builtin_amdgcn_cvt_pk_f32_fp8(v.y, true);  a[6] = fmaf(m, p.x, a[6]); a[7] = fmaf(m, p.y, a[7]);
}

__global__ __launch_bounds__(256) void agg_fp8_256(const int* __restrict__ rowptr,
                                                   const int* __restrict__ col,
                                                   const float* __restrict__ invdeg,
                                                   const unsigned char* __restrict__ H8,
                                                   unsigned short* __restrict__ out, int ostride, int N) {
    int wid = (blockIdx.x * blockDim.x + threadIdx.x) >> 6;
    int lane = threadIdx.x & 63;
    if (wid >= N) return;
    int half = lane >> 5;
    int sub = lane & 31;
    const unsigned char* Ho = H8 + sub * 8;
    int s = rowptr[wid], e = rowptr[wid + 1];
    float a[8] = {0.f, 0.f, 0.f, 0.f, 0.f, 0.f, 0.f, 0.f};
    for (int j = s + half; j < e; j += 8) {
        int j1 = (j + 2 < e) ? j + 2 : j;
        int j2 = (j + 4 < e) ? j + 4 : j;
        int j3 = (j + 6 < e) ? j + 6 : j;
        float m1 = (j + 2 < e) ? 1.f : 0.f;
        float m2 = (j + 4 < e) ? 1.f : 0.f;
        float m3 = (j + 6 < e) ? 1.f : 0.f;
        int c0 = col[j], c1 = col[j1], c2 = col[j2], c3 = col[j3];
        uint2 v0 = *(const uint2*)(Ho + (size_t)c0 * 256);
        uint2 v1 = *(const uint2*)(Ho + (size_t)c1 * 256);
        uint2 v2 = *(const uint2*)(Ho + (size_t)c2 * 256);
        uint2 v3 = *(const uint2*)(Ho + (size_t)c3 * 256);
        accum_fp8(v0, 1.f, a);
        accum_fp8(v1, m1, a);
        accum_fp8(v2, m2, a);
        accum_fp8(v3, m3, a);
    }
#pragma unroll
    for (int i = 0; i < 8; i++) a[i] += __shfl_xor(a[i], 32, 64);
    if (half == 0) {
        float inv = invdeg[wid];
        uint4 o;
        o.x = (unsigned)f2bf(a[0] * inv) | ((unsigned)f2bf(a[1] * inv) << 16);
        o.y = (unsigned)f2bf(a[2] * inv) | ((unsigned)f2bf(a[3] * inv) << 16);
        o.z = (unsigned)f2bf(a[4] * inv) | ((unsigned)f2bf(a[5] * inv) << 16);
        o.w = (unsigned)f2bf(a[6] * inv) | ((unsigned)f2bf(a[7] * inv) << 16);
        *(uint4*)(out + (size_t)wid * ostride + sub * 8) = o;
    }
}
#endif

// final: out = mean-agg(T bf16 [N,128]) + R fp32 [N,128], fp32 out; predicated unroll
__global__ __launch_bounds__(256) void agg_final_v3(const int* __restrict__ rowptr,
                                                    const int* __restrict__ col,
                                                    const float* __restrict__ invdeg,
                                                    const unsigned short* __restrict__ T,
                                                    const float* __restrict__ R,
                                                    float* __restrict__ out, int N) {
    int wid = (blockIdx.x * blockDim.x + threadIdx.x) >> 6;
    int lane = threadIdx.x & 63;
    if (wid >= N) return;
    int half = lane >> 5;
    int sub = lane & 31;
    const unsigned short* To = T + sub * 4;
    int s = rowptr[wid], e = rowptr[wid + 1];
    float a0 = 0.f, a1 = 0.f, a2 = 0.f, a3 = 0.f;
    for (int j = s + half; j < e; j += 8) {
        int j1 = (j + 2 < e) ? j + 2 : j;
        int j2 = (j + 4 < e) ? j + 4 : j;
        int j3 = (j + 6 < e) ? j + 6 : j;
        float m1 = (j + 2 < e) ? 1.f : 0.f;
        float m2 = (j + 4 < e) ? 1.f : 0.f;
        float m3 = (j + 6 < e) ? 1.f : 0.f;
        int c0 = col[j], c1 = col[j1], c2 = col[j2], c3 = col[j3];
        uint2 v0 = *(const uint2*)(To + (size_t)c0 * 128);
        uint2 v1 = *(const uint2*)(To + (size_t)c1 * 128);
        uint2 v2 = *(const uint2*)(To + (size_t)c2 * 128);
        uint2 v3 = *(const uint2*)(To + (size_t)c3 * 128);
        a0 += bf2f_lo(v0.x); a1 += bf2f_hi(v0.x); a2 += bf2f_lo(v0.y); a3 += bf2f_hi(v0.y);
        a0 = fmaf(m1, bf2f_lo(v1.x), a0); a1 = fmaf(m1, bf2f_hi(v1.x), a1);
        a2 = fmaf(m1, bf2f_lo(v1.y), a2); a3 = fmaf(m1, bf2f_hi(v1.y), a3);
        a0 = fmaf(m2, bf2f_lo(v2.x), a0); a1 = fmaf(m2, bf2f_hi(v2.x), a1);
        a2 = fmaf(m2, bf2f_lo(v2.y), a2); a3 = fmaf(m2, bf2f_hi(v2.y), a3);
        a0 = fmaf(m3, bf2f_lo(v3.x), a0); a1 = fmaf(m3, bf2f_hi(v3.x), a1);
        a2 = fmaf(m3, bf2f_lo(v3.y), a2); a3 = fmaf(m3, bf2f_hi(v3.y), a3);
    }
    a0 += __shfl_xor(a0, 32, 64);
    a1 += __shfl_xor(a1, 32, 64);
    a2 += __shfl_xor(a2, 32, 64);
    a3 += __shfl_xor(a3, 32, 64);
    if (half == 0) {
        float inv = invdeg[wid];
        float4 r = *(const float4*)(R + (size_t)wid * 128 + sub * 4);
        float4 o;
        o.x = a0 * inv + r.x;
        o.y = a1 * inv + r.y;
        o.z = a2 * inv + r.z;
        o.w = a3 * inv + r.w;
        *(float4*)(out + (size_t)wid * 128 + sub * 4) = o;
    }
}

// ================= bf16 MFMA GEMM, XOR-swizzled LDS + bounce epilogue =================
template <int KIT, int SPLIT>
__global__ __launch_bounds__(256) void gemm_lds(const unsigned short* __restrict__ A, int lda,
                                                const unsigned short* __restrict__ B, int ldb,
                                                const float* __restrict__ bias,
                                                unsigned short* __restrict__ C0, int ldc0,
                                                float* __restrict__ C1, int M) {
    __shared__ __align__(16) char smem[34816];  // max(staging 32KB, bounce 4*64*34*4)
    unsigned short* sA = (unsigned short*)smem;      // [128 rows][8 chunks][8 elems]
    unsigned short* sB = sA + 128 * 64;
    int t = threadIdx.x;
    int lane = t & 63, w = t >> 6;
    int bm = blockIdx.x * 128, bn = blockIdx.y * 128;
    int wm = (w >> 1) * 64, wn = (w & 1) * 64;
    int m16 = lane & 15, kq = lane >> 4;

    floatx4 acc[4][4];
#pragma unroll
    for (int i = 0; i < 4; i++)
#pragma unroll
        for (int j = 0; j < 4; j++) acc[i][j] = (floatx4){0.f, 0.f, 0.f, 0.f};

    const int c_row = t >> 3;                  // staging row (mod 32)
    const int kc = (t & 7) ^ (c_row & 7);      // logical k-chunk for this thread's slot
    const int srcOff = kc * 8;
    const int fsw = (m16 & 7);                 // fragment-read swizzle key

    for (int kt = 0; kt < KIT; kt++) {
        int k0 = kt * 64;
#pragma unroll
        for (int i = 0; i < 4; i++) {
            int rowA = bm + i * 32 + c_row;
            if (rowA > M - 1) rowA = M - 1;    // clamp; output rows masked at store
            gl_lds16(A + (size_t)rowA * lda + k0 + srcOff, (void*)&sA[(size_t)(i * 256 + t) * 8]);
            gl_lds16(B + (size_t)(bn + i * 32 + c_row) * ldb + k0 + srcOff,
                     (void*)&sB[(size_t)(i * 256 + t) * 8]);
        }
        __syncthreads();
#pragma unroll
        for (int ks = 0; ks < 2; ks++) {
            int kcl = (ks << 2) | kq;
            bf16x8 af[4], bfr[4];
#pragma unroll
            for (int mi = 0; mi < 4; mi++)
                af[mi] = *(const bf16x8*)&sA[(wm + mi * 16 + m16) * 64 + (kcl ^ fsw) * 8];
#pragma unroll
            for (int ni = 0; ni < 4; ni++)
                bfr[ni] = *(const bf16x8*)&sB[(wn + ni * 16 + m16) * 64 + (kcl ^ fsw) * 8];
#pragma unroll
            for (int mi = 0; mi < 4; mi++)
#pragma unroll
                for (int ni = 0; ni < 4; ni++)
                    acc[mi][ni] = __builtin_amdgcn_mfma_f32_16x16x32_bf16(af[mi], bfr[ni], acc[mi][ni], 0, 0, 0);
        }
        __syncthreads();
    }

    // ---- bounce epilogue: 2 halves of 32 cols through per-wave LDS ----
    float* wb = (float*)smem + w * (64 * 34);
    const float* bias0 = (SPLIT == 0) ? bias : ((bn == 0) ? nullptr : bias);
#pragma unroll
    for (int h = 0; h < 2; h++) {
#pragma unroll
        for (int nj = 0; nj < 2; nj++) {
            int ni = h * 2 + nj;
#pragma unroll
            for (int mi = 0; mi < 4; mi++)
#pragma unroll
                for (int r = 0; r < 4; r++)
                    wb[(mi * 16 + kq * 4 + r) * 34 + nj * 16 + m16] = acc[mi][ni][r];
        }
        asm volatile("s_waitcnt lgkmcnt(0)" ::: "memory");
        if (SPLIT == 0 || bn == 0) {
            int rsub = lane >> 2, c8 = (lane & 3) * 8;
            int ldc = (SPLIT == 0) ? ldc0 : 128;
            int gcol = ((SPLIT == 0) ? bn : 0) + wn + h * 32 + c8;
            float bv[8];
#pragma unroll
            for (int j = 0; j < 8; j++) bv[j] = bias0 ? bias0[gcol + j] : 0.f;
#pragma unroll
            for (int it = 0; it < 4; it++) {
                int rr = it * 16 + rsub;
                int grow = bm + wm + rr;
                float v0 = wb[rr * 34 + c8 + 0] + bv[0];
                float v1 = wb[rr * 34 + c8 + 1] + bv[1];
                float v2 = wb[rr * 34 + c8 + 2] + bv[2];
                float v3 = wb[rr * 34 + c8 + 3] + bv[3];
                float v4 = wb[rr * 34 + c8 + 4] + bv[4];
                float v5 = wb[rr * 34 + c8 + 5] + bv[5];
                float v6 = wb[rr * 34 + c8 + 6] + bv[6];
                float v7 = wb[rr * 34 + c8 + 7] + bv[7];
                uint4 o;
                o.x = (unsigned)f2bf(v0) | ((unsigned)f2bf(v1) << 16);
                o.y = (unsigned)f2bf(v2) | ((unsigned)f2bf(v3) << 16);
                o.z = (unsigned)f2bf(v4) | ((unsigned)f2bf(v5) << 16);
                o.w = (unsigned)f2bf(v6) | ((unsigned)f2bf(v7) << 16);
                if (grow < M) *(uint4*)(C0 + (size_t)grow * ldc + gcol) = o;
            }
        } else {
            int rsub = lane >> 3, c4 = (lane & 7) * 4;
            int gcol = wn + h * 32 + c4;
            float bv[4];
#pragma unroll
            for (int j = 0; j < 4; j++) bv[j] = bias0[gcol + j];
#pragma unroll
            for (int it = 0; it < 8; it++) {
                int rr = it * 8 + rsub;
                int grow = bm + wm + rr;
                float4 o;
                o.x = wb[rr * 34 + c4 + 0] + bv[0];
                o.y = wb[rr * 34 + c4 + 1] + bv[1];
                o.z = wb[rr * 34 + c4 + 2] + bv[2];
                o.w = wb[rr * 34 + c4 + 3] + bv[3];
                if (grow < M) *(float4*)(C1 + (size_t)grow * 128 + gcol) = o;
            }
        }
        if (h == 0) asm volatile("s_waitcnt lgkmcnt(0)" ::: "memory");
    }
}

// ================= LayerNorm(256)+ReLU+add, bf16 I/O, optional fp8 shadow out =================
__global__ __launch_bounds__(256) void ln_fuse2(const unsigned short* __restrict__ u, int ustride,
                                                const unsigned short* __restrict__ a, int astride,
                                                const float* __restrict__ g, const float* __restrict__ b,
                                                unsigned short* __restrict__ out, int ostride,
                                                unsigned char* __restrict__ h8, int N) {
    int row = (blockIdx.x * blockDim.x + threadIdx.x) >> 6;
    int lane = threadIdx.x & 63;
    if (row >= N) return;
    uint2 uv = *(const uint2*)(u + (size_t)row * ustride + lane * 4);
    float v0 = bf2f_lo(uv.x), v1 = bf2f_hi(uv.x), v2 = bf2f_lo(uv.y), v3 = bf2f_hi(uv.y);
    float s = (v0 + v1) + (v2 + v3);
    float sq = (v0 * v0 + v1 * v1) + (v2 * v2 + v3 * v3);
    for (int off = 1; off < 64; off <<= 1) {
        s += __shfl_xor(s, off, 64);
        sq += __shfl_xor(sq, off, 64);
    }
    float mu = s * (1.f / 256.f);
    float var = sq * (1.f / 256.f) - mu * mu;
    float rs = rsqrtf(var + 1e-5f);
    float4 gv = *(const float4*)(g + lane * 4);
    float4 bv = *(const float4*)(b + lane * 4);
    uint2 av = *(const uint2*)(a + (size_t)row * astride + lane * 4);
    float a0 = bf2f_lo(av.x), a1 = bf2f_hi(av.x), a2 = bf2f_lo(av.y), a3 = bf2f_hi(av.y);
    float o0 = fmaxf((v0 - mu) * rs * gv.x + bv.x, 0.f) + a0;
    float o1 = fmaxf((v1 - mu) * rs * gv.y + bv.y, 0.f) + a1;
    float o2 = fmaxf((v2 - mu) * rs * gv.z + bv.z, 0.f) + a2;
    float o3 = fmaxf((v3 - mu) * rs * gv.w + bv.w, 0.f) + a3;
    ushort4 o;
    o.x = f2bf(o0); o.y = f2bf(o1); o.z = f2bf(o2); o.w = f2bf(o3);
    *(ushort4*)(out + (size_t)row * ostride + lane * 4) = o;
#if HAS_FP8_CVT
    if (h8) {
        unsigned wpk = 0;
        wpk = __builtin_amdgcn_cvt_pk_fp8_f32(o0, o1, wpk, false);
        wpk = __builtin_amdgcn_cvt_pk_fp8_f32(o2, o3, wpk, true);
        *(unsigned*)(h8 + (size_t)row * 256 + lane * 4) = wpk;
    }
#endif
}

// ================= launch =================
extern "C" void kernel_launch(void* const* d_in, const int* in_sizes, int n_in,
                              void* d_out, int out_size, void* d_ws, size_t ws_size,
                              hipStream_t stream) {
    const float* x   = (const float*)d_in[0];
    const int*   ei  = (const int*)d_in[1];
    const float* W1l = (const float*)d_in[2];
    const float* b1l = (const float*)d_in[3];
    const float* W1r = (const float*)d_in[4];
    const float* g1  = (const float*)d_in[5];
    const float* be1 = (const float*)d_in[6];
    const float* Wsk = (const float*)d_in[7];
    const float* bsk = (const float*)d_in[8];
    const float* W2l = (const float*)d_in[9];
    const float* b2l = (const float*)d_in[10];
    const float* W2r = (const float*)d_in[11];
    const float* g2  = (const float*)d_in[12];
    const float* be2 = (const float*)d_in[13];
    const float* W3l = (const float*)d_in[14];
    const float* b3l = (const float*)d_in[15];
    const float* W3r = (const float*)d_in[16];

    const int N = in_sizes[0] / 128;
    const int E = in_sizes[1] / 2;
    const int* src = ei;
    const int* dst = ei + E;

    char* p = (char*)d_ws;
    auto alloc = [&](size_t bytes) {
        void* r = (void*)p;
        p += (bytes + 255) & ~(size_t)255;
        return r;
    };
    int*   cnt    = (int*)alloc(sizeof(int) * N);
    int*   rowptr = (int*)alloc(sizeof(int) * (N + 1));
    int*   cursor = (int*)alloc(sizeof(int) * N);
    float* invdeg = (float*)alloc(sizeof(float) * N);
    int*   col    = (int*)alloc(sizeof(int) * E);
    int*   bsum   = (int*)alloc(sizeof(int) * 256);
    int*   boff   = (int*)alloc(sizeof(int) * 256);
    unsigned short* A1cat = (unsigned short*)alloc(sizeof(short) * (size_t)N * 256);  // [agg1|x]; later t3
    unsigned short* A2cat = (unsigned short*)alloc(sizeof(short) * (size_t)N * 512);  // [agg2|h] -> [h2|h]
    unsigned short* U1    = (unsigned short*)alloc(sizeof(short) * (size_t)N * 512);  // [u1|s] bf16; later u2
    float* r3 = (float*)alloc(sizeof(float) * (size_t)N * 128);
    unsigned char* H8 = (unsigned char*)alloc((size_t)N * 256);                       // fp8 h shadow
    unsigned short* WtC = (unsigned short*)alloc(sizeof(short) * 512 * 256);
    unsigned short* Wt2 = (unsigned short*)alloc(sizeof(short) * 256 * 512);
    unsigned short* Wt3 = (unsigned short*)alloc(sizeof(short) * 256 * 256);
    float* biasC = (float*)alloc(sizeof(float) * 512);
    unsigned short* t3 = A1cat;
    unsigned short* u2 = U1;

    // ---- CSR build ----
    hipMemsetAsync(cnt, 0, sizeof(int) * N, stream);
    hist_kernel<<<(E + 255) / 256, 256, 0, stream>>>(dst, cnt, E);
    int NB = (N + SCAN_CHUNK - 1) / SCAN_CHUNK;
    scan_blocksums<<<NB, 256, 0, stream>>>(cnt, bsum, N);
    scan_bsums<<<1, 256, 0, stream>>>(bsum, boff, NB, rowptr, N, E);
    scan_final<<<NB, 256, 0, stream>>>(cnt, boff, rowptr, cursor, invdeg, N);
    scatter_kernel<<<(E + 255) / 256, 256, 0, stream>>>(src, dst, cursor, col, E);

    // ---- prep ----
    prep_weights<<<(328192 + 255) / 256, 256, 0, stream>>>(W1l, W1r, Wsk, W2l, W2r, W3l, W3r,
                                                           b1l, bsk, WtC, Wt2, Wt3, biasC);
    cvt_x_kernel<<<((N * 128) + 255) / 256, 256, 0, stream>>>(x, A1cat, N * 128);

    int aggBlocks = (N + 3) / 4;
    int mBlocks = (N + 127) / 128;

    // ---- layer 1 ----
    agg_bf16_v3<<<dim3(aggBlocks, 1), 256, 0, stream>>>(rowptr, col, invdeg, A1cat + 128, 256, A1cat, 256, N);
    gemm_lds<4, 0><<<dim3(mBlocks, 4), 256, 0, stream>>>(A1cat, 256, WtC, 256, biasC, U1, 512, nullptr, N);
    // h = relu(LN(u1)) + s -> A2cat right half (+ fp8 shadow for the layer-2 gather)
    ln_fuse2<<<aggBlocks, 256, 0, stream>>>(U1, 512, U1 + 256, 512, g1, be1, A2cat + 256, 512, H8, N);

    // ---- layer 2 ----
#if HAS_FP8_CVT
    agg_fp8_256<<<aggBlocks, 256, 0, stream>>>(rowptr, col, invdeg, H8, A2cat, 512, N);
#else
    agg_bf16_v3<<<dim3(aggBlocks, 2), 256, 0, stream>>>(rowptr, col, invdeg, A2cat + 256, 512, A2cat, 512, N);
#endif
    gemm_lds<8, 0><<<dim3(mBlocks, 2), 256, 0, stream>>>(A2cat, 512, Wt2, 512, b2l, u2, 256, nullptr, N);
    ln_fuse2<<<aggBlocks, 256, 0, stream>>>(u2, 256, A2cat + 256, 512, g2, be2, A2cat, 512, nullptr, N);

    // ---- layer 3: split GEMM -> t3 (bf16) + r3 (fp32+bias) ----
    gemm_lds<4, 1><<<dim3(mBlocks, 2), 256, 0, stream>>>(A2cat, 512, Wt3, 256, b3l, t3, 128, r3, N);
    agg_final_v3<<<aggBlocks, 256, 0, stream>>>(rowptr, col, invdeg, t3, r3, (float*)d_out, N);
}

// Round 9
// 389.342 us; speedup vs baseline: 1.8047x; 1.0540x over previous
//
#include <hip/hip_runtime.h>

// ---------------- problem dims (fixed by reference) ----------------
// N=50000, E=640000, DIN=128, DH=256, DOUT=128

typedef float floatx4 __attribute__((ext_vector_type(4)));
typedef float floatx2 __attribute__((ext_vector_type(2)));
typedef short bf16x8 __attribute__((ext_vector_type(8)));

__device__ inline unsigned short f2bf(float f) {
    unsigned u = __float_as_uint(f);
    unsigned r = (u + 0x7fffu + ((u >> 16) & 1u)) >> 16;  // RNE
    return (unsigned short)r;
}
__device__ inline float bf2f_lo(unsigned v) { return __uint_as_float(v << 16); }
__device__ inline float bf2f_hi(unsigned v) { return __uint_as_float(v & 0xffff0000u); }

__device__ inline void gl_lds16(const void* g, void* l) {
    __builtin_amdgcn_global_load_lds((const __attribute__((address_space(1))) unsigned int*)g,
                                     (__attribute__((address_space(3))) unsigned int*)l,
                                     16, 0, 0);
}

// ================= CSR build =================
__global__ void hist_kernel(const int* __restrict__ dst, int* __restrict__ cnt, int E) {
    int i = blockIdx.x * blockDim.x + threadIdx.x;
    if (i < E) atomicAdd(&cnt[dst[i]], 1);
}

#define SCAN_CHUNK 2048

__global__ __launch_bounds__(256) void scan_blocksums(const int* __restrict__ cnt,
                                                      int* __restrict__ bsum, int N) {
    __shared__ int sh[256];
    int t = threadIdx.x;
    int base = blockIdx.x * SCAN_CHUNK + t * 8;
    int s = 0;
#pragma unroll
    for (int i = 0; i < 8; i++) {
        int idx = base + i;
        if (idx < N) s += cnt[idx];
    }
    sh[t] = s;
    __syncthreads();
    for (int off = 1; off < 256; off <<= 1) {
        int v = (t >= off) ? sh[t - off] : 0;
        __syncthreads();
        sh[t] += v;
        __syncthreads();
    }
    if (t == 255) bsum[blockIdx.x] = sh[255];
}

__global__ __launch_bounds__(256) void scan_bsums(const int* __restrict__ bsum,
                                                  int* __restrict__ boff, int NB,
                                                  int* __restrict__ rowptr, int N, int E) {
    __shared__ int sh[256];
    int t = threadIdx.x;
    int v = (t < NB) ? bsum[t] : 0;
    sh[t] = v;
    __syncthreads();
    for (int off = 1; off < 256; off <<= 1) {
        int u = (t >= off) ? sh[t - off] : 0;
        __syncthreads();
        sh[t] += u;
        __syncthreads();
    }
    if (t < NB) boff[t] = sh[t] - v;
    if (t == 0) rowptr[N] = E;
}

__global__ __launch_bounds__(256) void scan_final(const int* __restrict__ cnt,
                                                  const int* __restrict__ boff,
                                                  int* __restrict__ rowptr,
                                                  int* __restrict__ cursor,
                                                  float* __restrict__ invdeg, int N) {
    __shared__ int sh[256];
    int t = threadIdx.x;
    int base = blockIdx.x * SCAN_CHUNK + t * 8;
    int c[8];
    int s = 0;
#pragma unroll
    for (int i = 0; i < 8; i++) {
        int idx = base + i;
        c[i] = (idx < N) ? cnt[idx] : 0;
        s += c[i];
    }
    sh[t] = s;
    __syncthreads();
    for (int off = 1; off < 256; off <<= 1) {
        int v = (t >= off) ? sh[t - off] : 0;
        __syncthreads();
        sh[t] += v;
        __syncthreads();
    }
    int run = boff[blockIdx.x] + sh[t] - s;
#pragma unroll
    for (int i = 0; i < 8; i++) {
        int idx = base + i;
        if (idx < N) {
            rowptr[idx] = run;
            cursor[idx] = run;
            invdeg[idx] = 1.0f / (float)(c[i] > 1 ? c[i] : 1);
            run += c[i];
        }
    }
}

__global__ void scatter_kernel(const int* __restrict__ src, const int* __restrict__ dst,
                               int* __restrict__ cursor, int* __restrict__ col, int E) {
    int i = blockIdx.x * blockDim.x + threadIdx.x;
    if (i < E) {
        int p = atomicAdd(&cursor[dst[i]], 1);
        col[p] = src[i];
    }
}

// ================= fused weight prep =================
// WtC [512,256]: rows 0-255 = [W1l;W1r]^T (u), rows 256-511 = [0;Wsk]^T (s)
// Wt2 [256,512]  ;  Wt3 [256,256]: rows 0-127 W3l^T, 128-255 W3r^T
// biasC [512] = [b1l | bsk]
__global__ void prep_weights(const float* __restrict__ W1l, const float* __restrict__ W1r,
                             const float* __restrict__ Wsk, const float* __restrict__ W2l,
                             const float* __restrict__ W2r, const float* __restrict__ W3l,
                             const float* __restrict__ W3r, const float* __restrict__ b1l,
                             const float* __restrict__ bsk,
                             unsigned short* __restrict__ WtC, unsigned short* __restrict__ Wt2,
                             unsigned short* __restrict__ Wt3, float* __restrict__ biasC) {
    int i = blockIdx.x * blockDim.x + threadIdx.x;
    if (i < 32768) {                        // W1l [128,256]
        int k = i >> 8, n = i & 255;
        WtC[n * 256 + k] = f2bf(W1l[i]);
    } else if (i < 65536) {                 // W1r
        int j = i - 32768, k = j >> 8, n = j & 255;
        WtC[n * 256 + 128 + k] = f2bf(W1r[j]);
    } else if (i < 98304) {                 // Wsk -> rows 256-511, k-half 128-255
        int j = i - 65536, k = j >> 8, n = j & 255;
        WtC[(256 + n) * 256 + 128 + k] = f2bf(Wsk[j]);
    } else if (i < 131072) {                // zero-fill rows 256-511, k-half 0-127
        int j = i - 98304, k = j >> 8, n = j & 255;
        WtC[(256 + n) * 256 + k] = 0;
    } else if (i < 196608) {                // W2l [256,256]
        int j = i - 131072, k = j >> 8, n = j & 255;
        Wt2[n * 512 + k] = f2bf(W2l[j]);
    } else if (i < 262144) {                // W2r
        int j = i - 196608, k = j >> 8, n = j & 255;
        Wt2[n * 512 + 256 + k] = f2bf(W2r[j]);
    } else if (i < 294912) {                // W3l [256,128]
        int j = i - 262144, k = j >> 7, n = j & 127;
        Wt3[n * 256 + k] = f2bf(W3l[j]);
    } else if (i < 327680) {                // W3r
        int j = i - 294912, k = j >> 7, n = j & 127;
        Wt3[(128 + n) * 256 + k] = f2bf(W3r[j]);
    } else if (i < 328192) {                // biasC [512]
        int j = i - 327680;
        biasC[j] = (j < 256) ? b1l[j] : bsk[j - 256];
    }
}

__global__ void cvt_x_kernel(const float* __restrict__ x, unsigned short* __restrict__ A1cat, int total) {
    int i = blockIdx.x * blockDim.x + threadIdx.x;
    if (i >= total) return;
    int r = i >> 7, c = i & 127;
    A1cat[(size_t)r * 256 + 128 + c] = f2bf(x[i]);
}

// ================= CSR mean aggregation, predicated unroll x4 =================
// one wave per (node, 128-col slice); lane>>5 = edge parity; always 4 gathers in flight.
__global__ __launch_bounds__(256) void agg_bf16_v3(const int* __restrict__ rowptr,
                                                   const int* __restrict__ col,
                                                   const float* __restrict__ invdeg,
                                                   const unsigned short* __restrict__ X, int xstride,
                                                   unsigned short* __restrict__ out, int ostride, int N) {
    int wid = (blockIdx.x * blockDim.x + threadIdx.x) >> 6;
    int lane = threadIdx.x & 63;
    if (wid >= N) return;
    int half = lane >> 5;
    int sub = lane & 31;
    int off = blockIdx.y * 128 + sub * 4;
    const unsigned short* Xo = X + off;
    int s = rowptr[wid], e = rowptr[wid + 1];
    float a0 = 0.f, a1 = 0.f, a2 = 0.f, a3 = 0.f;
    for (int j = s + half; j < e; j += 8) {
        int j1 = (j + 2 < e) ? j + 2 : j;
        int j2 = (j + 4 < e) ? j + 4 : j;
        int j3 = (j + 6 < e) ? j + 6 : j;
        float m1 = (j + 2 < e) ? 1.f : 0.f;
        float m2 = (j + 4 < e) ? 1.f : 0.f;
        float m3 = (j + 6 < e) ? 1.f : 0.f;
        int c0 = col[j], c1 = col[j1], c2 = col[j2], c3 = col[j3];
        uint2 v0 = *(const uint2*)(Xo + (size_t)c0 * xstride);
        uint2 v1 = *(const uint2*)(Xo + (size_t)c1 * xstride);
        uint2 v2 = *(const uint2*)(Xo + (size_t)c2 * xstride);
        uint2 v3 = *(const uint2*)(Xo + (size_t)c3 * xstride);
        a0 += bf2f_lo(v0.x); a1 += bf2f_hi(v0.x); a2 += bf2f_lo(v0.y); a3 += bf2f_hi(v0.y);
        a0 = fmaf(m1, bf2f_lo(v1.x), a0); a1 = fmaf(m1, bf2f_hi(v1.x), a1);
        a2 = fmaf(m1, bf2f_lo(v1.y), a2); a3 = fmaf(m1, bf2f_hi(v1.y), a3);
        a0 = fmaf(m2, bf2f_lo(v2.x), a0); a1 = fmaf(m2, bf2f_hi(v2.x), a1);
        a2 = fmaf(m2, bf2f_lo(v2.y), a2); a3 = fmaf(m2, bf2f_hi(v2.y), a3);
        a0 = fmaf(m3, bf2f_lo(v3.x), a0); a1 = fmaf(m3, bf2f_hi(v3.x), a1);
        a2 = fmaf(m3, bf2f_lo(v3.y), a2); a3 = fmaf(m3, bf2f_hi(v3.y), a3);
    }
    a0 += __shfl_xor(a0, 32, 64);
    a1 += __shfl_xor(a1, 32, 64);
    a2 += __shfl_xor(a2, 32, 64);
    a3 += __shfl_xor(a3, 32, 64);
    if (half == 0) {
        float inv = invdeg[wid];
        ushort4 o;
        o.x = f2bf(a0 * inv); o.y = f2bf(a1 * inv);
        o.z = f2bf(a2 * inv); o.w = f2bf(a3 * inv);
        *(ushort4*)(out + (size_t)wid * ostride + off) = o;
    }
}

// layer-2 agg over OCP-e4m3 fp8 h-table [N,256] (256B rows). One wave covers the full
// row: 32 lanes x 8B; lane>>5 = edge parity; predicated unroll x4 -> 4 gathers in flight.
__device__ inline void accum_fp8(uint2 v, float m, float* a) {
    floatx2 p;
    p = __builtin_amdgcn_cvt_pk_f32_fp8(v.x, false); a[0] = fmaf(m, p.x, a[0]); a[1] = fmaf(m, p.y, a[1]);
    p = __builtin_amdgcn_cvt_pk_f32_fp8(v.x, true);  a[2] = fmaf(m, p.x, a[2]); a[3] = fmaf(m, p.y, a[3]);
    p = __builtin_amdgcn_cvt_pk_f32_fp8(v.y, false); a[4] = fmaf(m, p.x, a[4]); a[5] = fmaf(m, p.y, a[5]);
    p = __builtin_amdgcn_cvt_pk_f32_fp8(v.y, true);  a[6] = fmaf(m, p.x, a[6]); a[7] = fmaf(m, p.y, a[7]);
}

__global__ __launch_bounds__(256) void agg_fp8_256(const int* __restrict__ rowptr,
                                                   const int* __restrict__ col,
                                                   const float* __restrict__ invdeg,
                                                   const unsigned char* __restrict__ H8,
                                                   unsigned short* __restrict__ out, int ostride, int N) {
    int wid = (blockIdx.x * blockDim.x + threadIdx.x) >> 6;
    int lane = threadIdx.x & 63;
    if (wid >= N) return;
    int half = lane >> 5;
    int sub = lane & 31;
    const unsigned char* Ho = H8 + sub * 8;
    int s = rowptr[wid], e = rowptr[wid + 1];
    float a[8] = {0.f, 0.f, 0.f, 0.f, 0.f, 0.f, 0.f, 0.f};
    for (int j = s + half; j < e; j += 8) {
        int j1 = (j + 2 < e) ? j + 2 : j;
        int j2 = (j + 4 < e) ? j + 4 : j;
        int j3 = (j + 6 < e) ? j + 6 : j;
        float m1 = (j + 2 < e) ? 1.f : 0.f;
        float m2 = (j + 4 < e) ? 1.f : 0.f;
        float m3 = (j + 6 < e) ? 1.f : 0.f;
        int c0 = col[j], c1 = col[j1], c2 = col[j2], c3 = col[j3];
        uint2 v0 = *(const uint2*)(Ho + (size_t)c0 * 256);
        uint2 v1 = *(const uint2*)(Ho + (size_t)c1 * 256);
        uint2 v2 = *(const uint2*)(Ho + (size_t)c2 * 256);
        uint2 v3 = *(const uint2*)(Ho + (size_t)c3 * 256);
        accum_fp8(v0, 1.f, a);
        accum_fp8(v1, m1, a);
        accum_fp8(v2, m2, a);
        accum_fp8(v3, m3, a);
    }
#pragma unroll
    for (int i = 0; i < 8; i++) a[i] += __shfl_xor(a[i], 32, 64);
    if (half == 0) {
        float inv = invdeg[wid];
        uint4 o;
        o.x = (unsigned)f2bf(a[0] * inv) | ((unsigned)f2bf(a[1] * inv) << 16);
        o.y = (unsigned)f2bf(a[2] * inv) | ((unsigned)f2bf(a[3] * inv) << 16);
        o.z = (unsigned)f2bf(a[4] * inv) | ((unsigned)f2bf(a[5] * inv) << 16);
        o.w = (unsigned)f2bf(a[6] * inv) | ((unsigned)f2bf(a[7] * inv) << 16);
        *(uint4*)(out + (size_t)wid * ostride + sub * 8) = o;
    }
}

// final: out = mean-agg(T bf16 [N,128]) + R fp32 [N,128], fp32 out; predicated unroll
__global__ __launch_bounds__(256) void agg_final_v3(const int* __restrict__ rowptr,
                                                    const int* __restrict__ col,
                                                    const float* __restrict__ invdeg,
                                                    const unsigned short* __restrict__ T,
                                                    const float* __restrict__ R,
                                                    float* __restrict__ out, int N) {
    int wid = (blockIdx.x * blockDim.x + threadIdx.x) >> 6;
    int lane = threadIdx.x & 63;
    if (wid >= N) return;
    int half = lane >> 5;
    int sub = lane & 31;
    const unsigned short* To = T + sub * 4;
    int s = rowptr[wid], e = rowptr[wid + 1];
    float a0 = 0.f, a1 = 0.f, a2 = 0.f, a3 = 0.f;
    for (int j = s + half; j < e; j += 8) {
        int j1 = (j + 2 < e) ? j + 2 : j;
        int j2 = (j + 4 < e) ? j + 4 : j;
        int j3 = (j + 6 < e) ? j + 6 : j;
        float m1 = (j + 2 < e) ? 1.f : 0.f;
        float m2 = (j + 4 < e) ? 1.f : 0.f;
        float m3 = (j + 6 < e) ? 1.f : 0.f;
        int c0 = col[j], c1 = col[j1], c2 = col[j2], c3 = col[j3];
        uint2 v0 = *(const uint2*)(To + (size_t)c0 * 128);
        uint2 v1 = *(const uint2*)(To + (size_t)c1 * 128);
        uint2 v2 = *(const uint2*)(To + (size_t)c2 * 128);
        uint2 v3 = *(const uint2*)(To + (size_t)c3 * 128);
        a0 += bf2f_lo(v0.x); a1 += bf2f_hi(v0.x); a2 += bf2f_lo(v0.y); a3 += bf2f_hi(v0.y);
        a0 = fmaf(m1, bf2f_lo(v1.x), a0); a1 = fmaf(m1, bf2f_hi(v1.x), a1);
        a2 = fmaf(m1, bf2f_lo(v1.y), a2); a3 = fmaf(m1, bf2f_hi(v1.y), a3);
        a0 = fmaf(m2, bf2f_lo(v2.x), a0); a1 = fmaf(m2, bf2f_hi(v2.x), a1);
        a2 = fmaf(m2, bf2f_lo(v2.y), a2); a3 = fmaf(m2, bf2f_hi(v2.y), a3);
        a0 = fmaf(m3, bf2f_lo(v3.x), a0); a1 = fmaf(m3, bf2f_hi(v3.x), a1);
        a2 = fmaf(m3, bf2f_lo(v3.y), a2); a3 = fmaf(m3, bf2f_hi(v3.y), a3);
    }
    a0 += __shfl_xor(a0, 32, 64);
    a1 += __shfl_xor(a1, 32, 64);
    a2 += __shfl_xor(a2, 32, 64);
    a3 += __shfl_xor(a3, 32, 64);
    if (half == 0) {
        float inv = invdeg[wid];
        float4 r = *(const float4*)(R + (size_t)wid * 128 + sub * 4);
        float4 o;
        o.x = a0 * inv + r.x;
        o.y = a1 * inv + r.y;
        o.z = a2 * inv + r.z;
        o.w = a3 * inv + r.w;
        *(float4*)(out + (size_t)wid * 128 + sub * 4) = o;
    }
}

// ================= bf16 MFMA GEMM, XOR-swizzled LDS + bounce epilogue =================
template <int KIT, int SPLIT>
__global__ __launch_bounds__(256) void gemm_lds(const unsigned short* __restrict__ A, int lda,
                                                const unsigned short* __restrict__ B, int ldb,
                                                const float* __restrict__ bias,
                                                unsigned short* __restrict__ C0, int ldc0,
                                                float* __restrict__ C1, int M) {
    __shared__ __align__(16) char smem[34816];  // max(staging 32KB, bounce 4*64*34*4)
    unsigned short* sA = (unsigned short*)smem;      // [128 rows][8 chunks][8 elems]
    unsigned short* sB = sA + 128 * 64;
    int t = threadIdx.x;
    int lane = t & 63, w = t >> 6;
    int bm = blockIdx.x * 128, bn = blockIdx.y * 128;
    int wm = (w >> 1) * 64, wn = (w & 1) * 64;
    int m16 = lane & 15, kq = lane >> 4;

    floatx4 acc[4][4];
#pragma unroll
    for (int i = 0; i < 4; i++)
#pragma unroll
        for (int j = 0; j < 4; j++) acc[i][j] = (floatx4){0.f, 0.f, 0.f, 0.f};

    const int c_row = t >> 3;                  // staging row (mod 32)
    const int kc = (t & 7) ^ (c_row & 7);      // logical k-chunk for this thread's slot
    const int srcOff = kc * 8;
    const int fsw = (m16 & 7);                 // fragment-read swizzle key

    for (int kt = 0; kt < KIT; kt++) {
        int k0 = kt * 64;
#pragma unroll
        for (int i = 0; i < 4; i++) {
            int rowA = bm + i * 32 + c_row;
            if (rowA > M - 1) rowA = M - 1;    // clamp; output rows masked at store
            gl_lds16(A + (size_t)rowA * lda + k0 + srcOff, (void*)&sA[(size_t)(i * 256 + t) * 8]);
            gl_lds16(B + (size_t)(bn + i * 32 + c_row) * ldb + k0 + srcOff,
                     (void*)&sB[(size_t)(i * 256 + t) * 8]);
        }
        __syncthreads();
#pragma unroll
        for (int ks = 0; ks < 2; ks++) {
            int kcl = (ks << 2) | kq;
            bf16x8 af[4], bfr[4];
#pragma unroll
            for (int mi = 0; mi < 4; mi++)
                af[mi] = *(const bf16x8*)&sA[(wm + mi * 16 + m16) * 64 + (kcl ^ fsw) * 8];
#pragma unroll
            for (int ni = 0; ni < 4; ni++)
                bfr[ni] = *(const bf16x8*)&sB[(wn + ni * 16 + m16) * 64 + (kcl ^ fsw) * 8];
#pragma unroll
            for (int mi = 0; mi < 4; mi++)
#pragma unroll
                for (int ni = 0; ni < 4; ni++)
                    acc[mi][ni] = __builtin_amdgcn_mfma_f32_16x16x32_bf16(af[mi], bfr[ni], acc[mi][ni], 0, 0, 0);
        }
        __syncthreads();
    }

    // ---- bounce epilogue: 2 halves of 32 cols through per-wave LDS ----
    float* wb = (float*)smem + w * (64 * 34);
    const float* bias0 = (SPLIT == 0) ? bias : ((bn == 0) ? nullptr : bias);
#pragma unroll
    for (int h = 0; h < 2; h++) {
#pragma unroll
        for (int nj = 0; nj < 2; nj++) {
            int ni = h * 2 + nj;
#pragma unroll
            for (int mi = 0; mi < 4; mi++)
#pragma unroll
                for (int r = 0; r < 4; r++)
                    wb[(mi * 16 + kq * 4 + r) * 34 + nj * 16 + m16] = acc[mi][ni][r];
        }
        asm volatile("s_waitcnt lgkmcnt(0)" ::: "memory");
        if (SPLIT == 0 || bn == 0) {
            int rsub = lane >> 2, c8 = (lane & 3) * 8;
            int ldc = (SPLIT == 0) ? ldc0 : 128;
            int gcol = ((SPLIT == 0) ? bn : 0) + wn + h * 32 + c8;
            float bv[8];
#pragma unroll
            for (int j = 0; j < 8; j++) bv[j] = bias0 ? bias0[gcol + j] : 0.f;
#pragma unroll
            for (int it = 0; it < 4; it++) {
                int rr = it * 16 + rsub;
                int grow = bm + wm + rr;
                float v0 = wb[rr * 34 + c8 + 0] + bv[0];
                float v1 = wb[rr * 34 + c8 + 1] + bv[1];
                float v2 = wb[rr * 34 + c8 + 2] + bv[2];
                float v3 = wb[rr * 34 + c8 + 3] + bv[3];
                float v4 = wb[rr * 34 + c8 + 4] + bv[4];
                float v5 = wb[rr * 34 + c8 + 5] + bv[5];
                float v6 = wb[rr * 34 + c8 + 6] + bv[6];
                float v7 = wb[rr * 34 + c8 + 7] + bv[7];
                uint4 o;
                o.x = (unsigned)f2bf(v0) | ((unsigned)f2bf(v1) << 16);
                o.y = (unsigned)f2bf(v2) | ((unsigned)f2bf(v3) << 16);
                o.z = (unsigned)f2bf(v4) | ((unsigned)f2bf(v5) << 16);
                o.w = (unsigned)f2bf(v6) | ((unsigned)f2bf(v7) << 16);
                if (grow < M) *(uint4*)(C0 + (size_t)grow * ldc + gcol) = o;
            }
        } else {
            int rsub = lane >> 3, c4 = (lane & 7) * 4;
            int gcol = wn + h * 32 + c4;
            float bv[4];
#pragma unroll
            for (int j = 0; j < 4; j++) bv[j] = bias0[gcol + j];
#pragma unroll
            for (int it = 0; it < 8; it++) {
                int rr = it * 8 + rsub;
                int grow = bm + wm + rr;
                float4 o;
                o.x = wb[rr * 34 + c4 + 0] + bv[0];
                o.y = wb[rr * 34 + c4 + 1] + bv[1];
                o.z = wb[rr * 34 + c4 + 2] + bv[2];
                o.w = wb[rr * 34 + c4 + 3] + bv[3];
                if (grow < M) *(float4*)(C1 + (size_t)grow * 128 + gcol) = o;
            }
        }
        if (h == 0) asm volatile("s_waitcnt lgkmcnt(0)" ::: "memory");
    }
}

// ================= LayerNorm(256)+ReLU+add, bf16 I/O, optional fp8 shadow out =================
__global__ __launch_bounds__(256) void ln_fuse2(const unsigned short* __restrict__ u, int ustride,
                                                const unsigned short* __restrict__ a, int astride,
                                                const float* __restrict__ g, const float* __restrict__ b,
                                                unsigned short* __restrict__ out, int ostride,
                                                unsigned char* __restrict__ h8, int N) {
    int row = (blockIdx.x * blockDim.x + threadIdx.x) >> 6;
    int lane = threadIdx.x & 63;
    if (row >= N) return;
    uint2 uv = *(const uint2*)(u + (size_t)row * ustride + lane * 4);
    float v0 = bf2f_lo(uv.x), v1 = bf2f_hi(uv.x), v2 = bf2f_lo(uv.y), v3 = bf2f_hi(uv.y);
    float s = (v0 + v1) + (v2 + v3);
    float sq = (v0 * v0 + v1 * v1) + (v2 * v2 + v3 * v3);
    for (int off = 1; off < 64; off <<= 1) {
        s += __shfl_xor(s, off, 64);
        sq += __shfl_xor(sq, off, 64);
    }
    float mu = s * (1.f / 256.f);
    float var = sq * (1.f / 256.f) - mu * mu;
    float rs = rsqrtf(var + 1e-5f);
    float4 gv = *(const float4*)(g + lane * 4);
    float4 bv = *(const float4*)(b + lane * 4);
    uint2 av = *(const uint2*)(a + (size_t)row * astride + lane * 4);
    float a0 = bf2f_lo(av.x), a1 = bf2f_hi(av.x), a2 = bf2f_lo(av.y), a3 = bf2f_hi(av.y);
    float o0 = fmaxf((v0 - mu) * rs * gv.x + bv.x, 0.f) + a0;
    float o1 = fmaxf((v1 - mu) * rs * gv.y + bv.y, 0.f) + a1;
    float o2 = fmaxf((v2 - mu) * rs * gv.z + bv.z, 0.f) + a2;
    float o3 = fmaxf((v3 - mu) * rs * gv.w + bv.w, 0.f) + a3;
    ushort4 o;
    o.x = f2bf(o0); o.y = f2bf(o1); o.z = f2bf(o2); o.w = f2bf(o3);
    *(ushort4*)(out + (size_t)row * ostride + lane * 4) = o;
    if (h8) {
        unsigned wpk = 0;
        wpk = __builtin_amdgcn_cvt_pk_fp8_f32(o0, o1, wpk, false);
        wpk = __builtin_amdgcn_cvt_pk_fp8_f32(o2, o3, wpk, true);
        *(unsigned*)(h8 + (size_t)row * 256 + lane * 4) = wpk;
    }
}

// ================= launch =================
extern "C" void kernel_launch(void* const* d_in, const int* in_sizes, int n_in,
                              void* d_out, int out_size, void* d_ws, size_t ws_size,
                              hipStream_t stream) {
    const float* x   = (const float*)d_in[0];
    const int*   ei  = (const int*)d_in[1];
    const float* W1l = (const float*)d_in[2];
    const float* b1l = (const float*)d_in[3];
    const float* W1r = (const float*)d_in[4];
    const float* g1  = (const float*)d_in[5];
    const float* be1 = (const float*)d_in[6];
    const float* Wsk = (const float*)d_in[7];
    const float* bsk = (const float*)d_in[8];
    const float* W2l = (const float*)d_in[9];
    const float* b2l = (const float*)d_in[10];
    const float* W2r = (const float*)d_in[11];
    const float* g2  = (const float*)d_in[12];
    const float* be2 = (const float*)d_in[13];
    const float* W3l = (const float*)d_in[14];
    const float* b3l = (const float*)d_in[15];
    const float* W3r = (const float*)d_in[16];

    const int N = in_sizes[0] / 128;
    const int E = in_sizes[1] / 2;
    const int* src = ei;
    const int* dst = ei + E;

    char* p = (char*)d_ws;
    auto alloc = [&](size_t bytes) {
        void* r = (void*)p;
        p += (bytes + 255) & ~(size_t)255;
        return r;
    };
    int*   cnt    = (int*)alloc(sizeof(int) * N);
    int*   rowptr = (int*)alloc(sizeof(int) * (N + 1));
    int*   cursor = (int*)alloc(sizeof(int) * N);
    float* invdeg = (float*)alloc(sizeof(float) * N);
    int*   col    = (int*)alloc(sizeof(int) * E);
    int*   bsum   = (int*)alloc(sizeof(int) * 256);
    int*   boff   = (int*)alloc(sizeof(int) * 256);
    unsigned short* A1cat = (unsigned short*)alloc(sizeof(short) * (size_t)N * 256);  // [agg1|x]; later t3
    unsigned short* A2cat = (unsigned short*)alloc(sizeof(short) * (size_t)N * 512);  // [agg2|h] -> [h2|h]
    unsigned short* U1    = (unsigned short*)alloc(sizeof(short) * (size_t)N * 512);  // [u1|s] bf16; later u2
    float* r3 = (float*)alloc(sizeof(float) * (size_t)N * 128);
    unsigned char* H8 = (unsigned char*)alloc((size_t)N * 256);                       // fp8 h shadow
    unsigned short* WtC = (unsigned short*)alloc(sizeof(short) * 512 * 256);
    unsigned short* Wt2 = (unsigned short*)alloc(sizeof(short) * 256 * 512);
    unsigned short* Wt3 = (unsigned short*)alloc(sizeof(short) * 256 * 256);
    float* biasC = (float*)alloc(sizeof(float) * 512);
    unsigned short* t3 = A1cat;
    unsigned short* u2 = U1;

    // ---- CSR build ----
    hipMemsetAsync(cnt, 0, sizeof(int) * N, stream);
    hist_kernel<<<(E + 255) / 256, 256, 0, stream>>>(dst, cnt, E);
    int NB = (N + SCAN_CHUNK - 1) / SCAN_CHUNK;
    scan_blocksums<<<NB, 256, 0, stream>>>(cnt, bsum, N);
    scan_bsums<<<1, 256, 0, stream>>>(bsum, boff, NB, rowptr, N, E);
    scan_final<<<NB, 256, 0, stream>>>(cnt, boff, rowptr, cursor, invdeg, N);
    scatter_kernel<<<(E + 255) / 256, 256, 0, stream>>>(src, dst, cursor, col, E);

    // ---- prep ----
    prep_weights<<<(328192 + 255) / 256, 256, 0, stream>>>(W1l, W1r, Wsk, W2l, W2r, W3l, W3r,
                                                           b1l, bsk, WtC, Wt2, Wt3, biasC);
    cvt_x_kernel<<<((N * 128) + 255) / 256, 256, 0, stream>>>(x, A1cat, N * 128);

    int aggBlocks = (N + 3) / 4;
    int mBlocks = (N + 127) / 128;

    // ---- layer 1 ----
    agg_bf16_v3<<<dim3(aggBlocks, 1), 256, 0, stream>>>(rowptr, col, invdeg, A1cat + 128, 256, A1cat, 256, N);
    gemm_lds<4, 0><<<dim3(mBlocks, 4), 256, 0, stream>>>(A1cat, 256, WtC, 256, biasC, U1, 512, nullptr, N);
    // h = relu(LN(u1)) + s -> A2cat right half (+ fp8 shadow for the layer-2 gather)
    ln_fuse2<<<aggBlocks, 256, 0, stream>>>(U1, 512, U1 + 256, 512, g1, be1, A2cat + 256, 512, H8, N);

    // ---- layer 2: fp8 gather (table 12.8 MB vs 51 MB bf16) ----
    agg_fp8_256<<<aggBlocks, 256, 0, stream>>>(rowptr, col, invdeg, H8, A2cat, 512, N);
    gemm_lds<8, 0><<<dim3(mBlocks, 2), 256, 0, stream>>>(A2cat, 512, Wt2, 512, b2l, u2, 256, nullptr, N);
    ln_fuse2<<<aggBlocks, 256, 0, stream>>>(u2, 256, A2cat + 256, 512, g2, be2, A2cat, 512, nullptr, N);

    // ---- layer 3: split GEMM -> t3 (bf16) + r3 (fp32+bias) ----
    gemm_lds<4, 1><<<dim3(mBlocks, 2), 256, 0, stream>>>(A2cat, 512, Wt3, 256, b3l, t3, 128, r3, N);
    agg_final_v3<<<aggBlocks, 256, 0, stream>>>(rowptr, col, invdeg, t3, r3, (float*)d_out, N);
}

// Round 10
// 376.832 us; speedup vs baseline: 1.8646x; 1.0332x over previous
//
#include <hip/hip_runtime.h>

// ---------------- problem dims (fixed by reference) ----------------
// N=50000, E=640000, DIN=128, DH=256, DOUT=128

typedef float floatx4 __attribute__((ext_vector_type(4)));
typedef float floatx2 __attribute__((ext_vector_type(2)));
typedef short bf16x8 __attribute__((ext_vector_type(8)));

__device__ inline unsigned short f2bf(float f) {
    unsigned u = __float_as_uint(f);
    unsigned r = (u + 0x7fffu + ((u >> 16) & 1u)) >> 16;  // RNE
    return (unsigned short)r;
}
__device__ inline float bf2f_lo(unsigned v) { return __uint_as_float(v << 16); }
__device__ inline float bf2f_hi(unsigned v) { return __uint_as_float(v & 0xffff0000u); }

__device__ inline void gl_lds16(const void* g, void* l) {
    __builtin_amdgcn_global_load_lds((const __attribute__((address_space(1))) unsigned int*)g,
                                     (__attribute__((address_space(3))) unsigned int*)l,
                                     16, 0, 0);
}

// ================= CSR build =================
__global__ void hist_kernel(const int* __restrict__ dst, int* __restrict__ cnt, int E) {
    int i = blockIdx.x * blockDim.x + threadIdx.x;
    if (i < E) atomicAdd(&cnt[dst[i]], 1);
}

#define SCAN_CHUNK 2048

__global__ __launch_bounds__(256) void scan_blocksums(const int* __restrict__ cnt,
                                                      int* __restrict__ bsum, int N) {
    __shared__ int sh[256];
    int t = threadIdx.x;
    int base = blockIdx.x * SCAN_CHUNK + t * 8;
    int s = 0;
#pragma unroll
    for (int i = 0; i < 8; i++) {
        int idx = base + i;
        if (idx < N) s += cnt[idx];
    }
    sh[t] = s;
    __syncthreads();
    for (int off = 1; off < 256; off <<= 1) {
        int v = (t >= off) ? sh[t - off] : 0;
        __syncthreads();
        sh[t] += v;
        __syncthreads();
    }
    if (t == 255) bsum[blockIdx.x] = sh[255];
}

__global__ __launch_bounds__(256) void scan_bsums(const int* __restrict__ bsum,
                                                  int* __restrict__ boff, int NB,
                                                  int* __restrict__ rowptr, int N, int E) {
    __shared__ int sh[256];
    int t = threadIdx.x;
    int v = (t < NB) ? bsum[t] : 0;
    sh[t] = v;
    __syncthreads();
    for (int off = 1; off < 256; off <<= 1) {
        int u = (t >= off) ? sh[t - off] : 0;
        __syncthreads();
        sh[t] += u;
        __syncthreads();
    }
    if (t < NB) boff[t] = sh[t] - v;
    if (t == 0) rowptr[N] = E;
}

__global__ __launch_bounds__(256) void scan_final(const int* __restrict__ cnt,
                                                  const int* __restrict__ boff,
                                                  int* __restrict__ rowptr,
                                                  int* __restrict__ cursor,
                                                  float* __restrict__ invdeg, int N) {
    __shared__ int sh[256];
    int t = threadIdx.x;
    int base = blockIdx.x * SCAN_CHUNK + t * 8;
    int c[8];
    int s = 0;
#pragma unroll
    for (int i = 0; i < 8; i++) {
        int idx = base + i;
        c[i] = (idx < N) ? cnt[idx] : 0;
        s += c[i];
    }
    sh[t] = s;
    __syncthreads();
    for (int off = 1; off < 256; off <<= 1) {
        int v = (t >= off) ? sh[t - off] : 0;
        __syncthreads();
        sh[t] += v;
        __syncthreads();
    }
    int run = boff[blockIdx.x] + sh[t] - s;
#pragma unroll
    for (int i = 0; i < 8; i++) {
        int idx = base + i;
        if (idx < N) {
            rowptr[idx] = run;
            cursor[idx] = run;
            invdeg[idx] = 1.0f / (float)(c[i] > 1 ? c[i] : 1);
            run += c[i];
        }
    }
}

__global__ void scatter_kernel(const int* __restrict__ src, const int* __restrict__ dst,
                               int* __restrict__ cursor, int* __restrict__ col, int E) {
    int i = blockIdx.x * blockDim.x + threadIdx.x;
    if (i < E) {
        int p = atomicAdd(&cursor[dst[i]], 1);
        col[p] = src[i];
    }
}

// ================= fused weight prep =================
// WtC [512,256]: rows 0-255 = [W1l;W1r]^T (u), rows 256-511 = [0;Wsk]^T (s)
// Wt2 [256,512]  ;  Wt3 [256,256]: rows 0-127 W3l^T, 128-255 W3r^T
// biasC [512] = [b1l | bsk]
__global__ void prep_weights(const float* __restrict__ W1l, const float* __restrict__ W1r,
                             const float* __restrict__ Wsk, const float* __restrict__ W2l,
                             const float* __restrict__ W2r, const float* __restrict__ W3l,
                             const float* __restrict__ W3r, const float* __restrict__ b1l,
                             const float* __restrict__ bsk,
                             unsigned short* __restrict__ WtC, unsigned short* __restrict__ Wt2,
                             unsigned short* __restrict__ Wt3, float* __restrict__ biasC) {
    int i = blockIdx.x * blockDim.x + threadIdx.x;
    if (i < 32768) {                        // W1l [128,256]
        int k = i >> 8, n = i & 255;
        WtC[n * 256 + k] = f2bf(W1l[i]);
    } else if (i < 65536) {                 // W1r
        int j = i - 32768, k = j >> 8, n = j & 255;
        WtC[n * 256 + 128 + k] = f2bf(W1r[j]);
    } else if (i < 98304) {                 // Wsk -> rows 256-511, k-half 128-255
        int j = i - 65536, k = j >> 8, n = j & 255;
        WtC[(256 + n) * 256 + 128 + k] = f2bf(Wsk[j]);
    } else if (i < 131072) {                // zero-fill rows 256-511, k-half 0-127
        int j = i - 98304, k = j >> 8, n = j & 255;
        WtC[(256 + n) * 256 + k] = 0;
    } else if (i < 196608) {                // W2l [256,256]
        int j = i - 131072, k = j >> 8, n = j & 255;
        Wt2[n * 512 + k] = f2bf(W2l[j]);
    } else if (i < 262144) {                // W2r
        int j = i - 196608, k = j >> 8, n = j & 255;
        Wt2[n * 512 + 256 + k] = f2bf(W2r[j]);
    } else if (i < 294912) {                // W3l [256,128]
        int j = i - 262144, k = j >> 7, n = j & 127;
        Wt3[n * 256 + k] = f2bf(W3l[j]);
    } else if (i < 327680) {                // W3r
        int j = i - 294912, k = j >> 7, n = j & 127;
        Wt3[(128 + n) * 256 + k] = f2bf(W3r[j]);
    } else if (i < 328192) {                // biasC [512]
        int j = i - 327680;
        biasC[j] = (j < 256) ? b1l[j] : bsk[j - 256];
    }
}

// x fp32 [N,128] -> bf16 into A1cat right half (stride 256) + fp8 shadow X8 [N,128]
__global__ void cvt_x2(const float* __restrict__ x, unsigned short* __restrict__ A1cat,
                       unsigned char* __restrict__ X8, int total32) {
    int i = blockIdx.x * blockDim.x + threadIdx.x;
    if (i >= total32) return;
    int r = i >> 5, c4 = (i & 31) * 4;
    float4 v = *(const float4*)(x + (size_t)r * 128 + c4);
    ushort4 o;
    o.x = f2bf(v.x); o.y = f2bf(v.y); o.z = f2bf(v.z); o.w = f2bf(v.w);
    *(ushort4*)(A1cat + (size_t)r * 256 + 128 + c4) = o;
    unsigned wpk = 0;
    wpk = __builtin_amdgcn_cvt_pk_fp8_f32(v.x, v.y, wpk, false);
    wpk = __builtin_amdgcn_cvt_pk_fp8_f32(v.z, v.w, wpk, true);
    *(unsigned*)(X8 + (size_t)r * 128 + c4) = wpk;
}

// ================= fp8 helpers =================
__device__ inline void accum_fp8(uint2 v, float m, float* a) {
    floatx2 p;
    p = __builtin_amdgcn_cvt_pk_f32_fp8(v.x, false); a[0] = fmaf(m, p.x, a[0]); a[1] = fmaf(m, p.y, a[1]);
    p = __builtin_amdgcn_cvt_pk_f32_fp8(v.x, true);  a[2] = fmaf(m, p.x, a[2]); a[3] = fmaf(m, p.y, a[3]);
    p = __builtin_amdgcn_cvt_pk_f32_fp8(v.y, false); a[4] = fmaf(m, p.x, a[4]); a[5] = fmaf(m, p.y, a[5]);
    p = __builtin_amdgcn_cvt_pk_f32_fp8(v.y, true);  a[6] = fmaf(m, p.x, a[6]); a[7] = fmaf(m, p.y, a[7]);
}

// layer-1 agg over fp8 x-table [N,128] (128B rows). 16 lanes x 8B cover a row;
// lane>>4 = edge quarter -> 4 edges in parallel; predicated unroll x4 -> 16 gathers in flight.
// Output bf16 into A1cat left half.
__global__ __launch_bounds__(256) void agg_fp8_128(const int* __restrict__ rowptr,
                                                   const int* __restrict__ col,
                                                   const float* __restrict__ invdeg,
                                                   const unsigned char* __restrict__ X8,
                                                   unsigned short* __restrict__ out, int ostride, int N) {
    int wid = (blockIdx.x * blockDim.x + threadIdx.x) >> 6;
    int lane = threadIdx.x & 63;
    if (wid >= N) return;
    int q = lane >> 4;       // 0..3 edge quarter
    int sub = lane & 15;     // 8B column chunk
    const unsigned char* Xo = X8 + sub * 8;
    int s = rowptr[wid], e = rowptr[wid + 1];
    float a[8] = {0.f, 0.f, 0.f, 0.f, 0.f, 0.f, 0.f, 0.f};
    for (int j = s + q; j < e; j += 16) {
        int j1 = (j + 4 < e) ? j + 4 : j;
        int j2 = (j + 8 < e) ? j + 8 : j;
        int j3 = (j + 12 < e) ? j + 12 : j;
        float m1 = (j + 4 < e) ? 1.f : 0.f;
        float m2 = (j + 8 < e) ? 1.f : 0.f;
        float m3 = (j + 12 < e) ? 1.f : 0.f;
        int c0 = col[j], c1 = col[j1], c2 = col[j2], c3 = col[j3];
        uint2 v0 = *(const uint2*)(Xo + (size_t)c0 * 128);
        uint2 v1 = *(const uint2*)(Xo + (size_t)c1 * 128);
        uint2 v2 = *(const uint2*)(Xo + (size_t)c2 * 128);
        uint2 v3 = *(const uint2*)(Xo + (size_t)c3 * 128);
        accum_fp8(v0, 1.f, a);
        accum_fp8(v1, m1, a);
        accum_fp8(v2, m2, a);
        accum_fp8(v3, m3, a);
    }
#pragma unroll
    for (int i = 0; i < 8; i++) {
        a[i] += __shfl_xor(a[i], 16, 64);
        a[i] += __shfl_xor(a[i], 32, 64);
    }
    if (q == 0) {
        float inv = invdeg[wid];
        uint4 o;
        o.x = (unsigned)f2bf(a[0] * inv) | ((unsigned)f2bf(a[1] * inv) << 16);
        o.y = (unsigned)f2bf(a[2] * inv) | ((unsigned)f2bf(a[3] * inv) << 16);
        o.z = (unsigned)f2bf(a[4] * inv) | ((unsigned)f2bf(a[5] * inv) << 16);
        o.w = (unsigned)f2bf(a[6] * inv) | ((unsigned)f2bf(a[7] * inv) << 16);
        *(uint4*)(out + (size_t)wid * ostride + sub * 8) = o;
    }
}

// layer-2 agg over fp8 h-table [N,256] (256B rows). 32 lanes x 8B; lane>>5 = edge parity.
__global__ __launch_bounds__(256) void agg_fp8_256(const int* __restrict__ rowptr,
                                                   const int* __restrict__ col,
                                                   const float* __restrict__ invdeg,
                                                   const unsigned char* __restrict__ H8,
                                                   unsigned short* __restrict__ out, int ostride, int N) {
    int wid = (blockIdx.x * blockDim.x + threadIdx.x) >> 6;
    int lane = threadIdx.x & 63;
    if (wid >= N) return;
    int half = lane >> 5;
    int sub = lane & 31;
    const unsigned char* Ho = H8 + sub * 8;
    int s = rowptr[wid], e = rowptr[wid + 1];
    float a[8] = {0.f, 0.f, 0.f, 0.f, 0.f, 0.f, 0.f, 0.f};
    for (int j = s + half; j < e; j += 8) {
        int j1 = (j + 2 < e) ? j + 2 : j;
        int j2 = (j + 4 < e) ? j + 4 : j;
        int j3 = (j + 6 < e) ? j + 6 : j;
        float m1 = (j + 2 < e) ? 1.f : 0.f;
        float m2 = (j + 4 < e) ? 1.f : 0.f;
        float m3 = (j + 6 < e) ? 1.f : 0.f;
        int c0 = col[j], c1 = col[j1], c2 = col[j2], c3 = col[j3];
        uint2 v0 = *(const uint2*)(Ho + (size_t)c0 * 256);
        uint2 v1 = *(const uint2*)(Ho + (size_t)c1 * 256);
        uint2 v2 = *(const uint2*)(Ho + (size_t)c2 * 256);
        uint2 v3 = *(const uint2*)(Ho + (size_t)c3 * 256);
        accum_fp8(v0, 1.f, a);
        accum_fp8(v1, m1, a);
        accum_fp8(v2, m2, a);
        accum_fp8(v3, m3, a);
    }
#pragma unroll
    for (int i = 0; i < 8; i++) a[i] += __shfl_xor(a[i], 32, 64);
    if (half == 0) {
        float inv = invdeg[wid];
        uint4 o;
        o.x = (unsigned)f2bf(a[0] * inv) | ((unsigned)f2bf(a[1] * inv) << 16);
        o.y = (unsigned)f2bf(a[2] * inv) | ((unsigned)f2bf(a[3] * inv) << 16);
        o.z = (unsigned)f2bf(a[4] * inv) | ((unsigned)f2bf(a[5] * inv) << 16);
        o.w = (unsigned)f2bf(a[6] * inv) | ((unsigned)f2bf(a[7] * inv) << 16);
        *(uint4*)(out + (size_t)wid * ostride + sub * 8) = o;
    }
}

// final: out = mean-agg(T bf16 [N,128]) + R fp32 [N,128], fp32 out; predicated unroll
__global__ __launch_bounds__(256) void agg_final_v3(const int* __restrict__ rowptr,
                                                    const int* __restrict__ col,
                                                    const float* __restrict__ invdeg,
                                                    const unsigned short* __restrict__ T,
                                                    const float* __restrict__ R,
                                                    float* __restrict__ out, int N) {
    int wid = (blockIdx.x * blockDim.x + threadIdx.x) >> 6;
    int lane = threadIdx.x & 63;
    if (wid >= N) return;
    int half = lane >> 5;
    int sub = lane & 31;
    const unsigned short* To = T + sub * 4;
    int s = rowptr[wid], e = rowptr[wid + 1];
    float a0 = 0.f, a1 = 0.f, a2 = 0.f, a3 = 0.f;
    for (int j = s + half; j < e; j += 8) {
        int j1 = (j + 2 < e) ? j + 2 : j;
        int j2 = (j + 4 < e) ? j + 4 : j;
        int j3 = (j + 6 < e) ? j + 6 : j;
        float m1 = (j + 2 < e) ? 1.f : 0.f;
        float m2 = (j + 4 < e) ? 1.f : 0.f;
        float m3 = (j + 6 < e) ? 1.f : 0.f;
        int c0 = col[j], c1 = col[j1], c2 = col[j2], c3 = col[j3];
        uint2 v0 = *(const uint2*)(To + (size_t)c0 * 128);
        uint2 v1 = *(const uint2*)(To + (size_t)c1 * 128);
        uint2 v2 = *(const uint2*)(To + (size_t)c2 * 128);
        uint2 v3 = *(const uint2*)(To + (size_t)c3 * 128);
        a0 += bf2f_lo(v0.x); a1 += bf2f_hi(v0.x); a2 += bf2f_lo(v0.y); a3 += bf2f_hi(v0.y);
        a0 = fmaf(m1, bf2f_lo(v1.x), a0); a1 = fmaf(m1, bf2f_hi(v1.x), a1);
        a2 = fmaf(m1, bf2f_lo(v1.y), a2); a3 = fmaf(m1, bf2f_hi(v1.y), a3);
        a0 = fmaf(m2, bf2f_lo(v2.x), a0); a1 = fmaf(m2, bf2f_hi(v2.x), a1);
        a2 = fmaf(m2, bf2f_lo(v2.y), a2); a3 = fmaf(m2, bf2f_hi(v2.y), a3);
        a0 = fmaf(m3, bf2f_lo(v3.x), a0); a1 = fmaf(m3, bf2f_hi(v3.x), a1);
        a2 = fmaf(m3, bf2f_lo(v3.y), a2); a3 = fmaf(m3, bf2f_hi(v3.y), a3);
    }
    a0 += __shfl_xor(a0, 32, 64);
    a1 += __shfl_xor(a1, 32, 64);
    a2 += __shfl_xor(a2, 32, 64);
    a3 += __shfl_xor(a3, 32, 64);
    if (half == 0) {
        float inv = invdeg[wid];
        float4 r = *(const float4*)(R + (size_t)wid * 128 + sub * 4);
        float4 o;
        o.x = a0 * inv + r.x;
        o.y = a1 * inv + r.y;
        o.z = a2 * inv + r.z;
        o.w = a3 * inv + r.w;
        *(float4*)(out + (size_t)wid * 128 + sub * 4) = o;
    }
}

// ================= bf16 MFMA GEMM v2: multi-panel, XOR-swizzled LDS, bounce epilogue ==========
// Block computes 128 rows x (128*NP) cols; A-tile staged ONCE for all NP B-panels.
// SPLIT=0: all panels -> bf16 C0(ldc0) + bias[bn0+p*128+..].
// SPLIT=1 (NP=2): panel0 -> bf16 C0(ldc 128, no bias); panel1 -> fp32 C1(ldc 128, +bias).
template <int KIT, int NP, int SPLIT>
__global__ __launch_bounds__(256) void gemm_lds2(const unsigned short* __restrict__ A, int lda,
                                                 const unsigned short* __restrict__ B, int ldb,
                                                 const float* __restrict__ bias,
                                                 unsigned short* __restrict__ C0, int ldc0,
                                                 float* __restrict__ C1, int M) {
    constexpr int STAGE = 128 * 64 * 2;  // bytes per tile (bf16)
    constexpr int SMEM_SZ = (STAGE * (1 + NP) > 34816) ? STAGE * (1 + NP) : 34816;
    __shared__ __align__(16) char smem[SMEM_SZ];
    unsigned short* sA = (unsigned short*)smem;
    int t = threadIdx.x;
    int lane = t & 63, w = t >> 6;
    int bm = blockIdx.x * 128;
    int bn0 = blockIdx.y * 128 * NP;
    int wm = (w >> 1) * 64, wn = (w & 1) * 64;
    int m16 = lane & 15, kq = lane >> 4;

    floatx4 acc[NP][4][4];
#pragma unroll
    for (int p = 0; p < NP; p++)
#pragma unroll
        for (int i = 0; i < 4; i++)
#pragma unroll
            for (int j = 0; j < 4; j++) acc[p][i][j] = (floatx4){0.f, 0.f, 0.f, 0.f};

    const int c_row = t >> 3;                  // staging row (mod 32)
    const int kc = (t & 7) ^ (c_row & 7);      // XOR-swizzled logical k-chunk
    const int srcOff = kc * 8;
    const int fsw = (m16 & 7);                 // fragment-read swizzle key

    for (int kt = 0; kt < KIT; kt++) {
        int k0 = kt * 64;
#pragma unroll
        for (int i = 0; i < 4; i++) {
            int rowA = bm + i * 32 + c_row;
            if (rowA > M - 1) rowA = M - 1;    // clamp; output rows masked at store
            gl_lds16(A + (size_t)rowA * lda + k0 + srcOff, (void*)&sA[(size_t)(i * 256 + t) * 8]);
#pragma unroll
            for (int p = 0; p < NP; p++)
                gl_lds16(B + (size_t)(bn0 + p * 128 + i * 32 + c_row) * ldb + k0 + srcOff,
                         (void*)&sA[(size_t)((p + 1) * 128 * 64) + (size_t)(i * 256 + t) * 8]);
        }
        __syncthreads();
#pragma unroll
        for (int ks = 0; ks < 2; ks++) {
            int kcl = (ks << 2) | kq;
            bf16x8 af[4];
#pragma unroll
            for (int mi = 0; mi < 4; mi++)
                af[mi] = *(const bf16x8*)&sA[(wm + mi * 16 + m16) * 64 + (kcl ^ fsw) * 8];
#pragma unroll
            for (int p = 0; p < NP; p++) {
                const unsigned short* sB = sA + (p + 1) * 128 * 64;
                bf16x8 bfr[4];
#pragma unroll
                for (int ni = 0; ni < 4; ni++)
                    bfr[ni] = *(const bf16x8*)&sB[(wn + ni * 16 + m16) * 64 + (kcl ^ fsw) * 8];
#pragma unroll
                for (int mi = 0; mi < 4; mi++)
#pragma unroll
                    for (int ni = 0; ni < 4; ni++)
                        acc[p][mi][ni] =
                            __builtin_amdgcn_mfma_f32_16x16x32_bf16(af[mi], bfr[ni], acc[p][mi][ni], 0, 0, 0);
            }
        }
        __syncthreads();
    }

    // ---- bounce epilogue: per panel, 2 halves of 32 cols through per-wave LDS ----
    float* wb = (float*)smem + w * (64 * 34);
#pragma unroll
    for (int p = 0; p < NP; p++) {
        const bool isF32 = (SPLIT == 1 && p == 1);
        const float* bp = (SPLIT == 0) ? (bias + bn0 + p * 128) : ((p == 0) ? nullptr : bias);
#pragma unroll
        for (int h = 0; h < 2; h++) {
#pragma unroll
            for (int nj = 0; nj < 2; nj++) {
                int ni = h * 2 + nj;
#pragma unroll
                for (int mi = 0; mi < 4; mi++)
#pragma unroll
                    for (int r = 0; r < 4; r++)
                        wb[(mi * 16 + kq * 4 + r) * 34 + nj * 16 + m16] = acc[p][mi][ni][r];
            }
            asm volatile("s_waitcnt lgkmcnt(0)" ::: "memory");
            if (!isF32) {
                int rsub = lane >> 2, c8 = (lane & 3) * 8;
                int ldc = (SPLIT == 0) ? ldc0 : 128;
                int lcol = wn + h * 32 + c8;
                int colbase = ((SPLIT == 0) ? bn0 + p * 128 : 0) + lcol;
                float bv[8];
#pragma unroll
                for (int j = 0; j < 8; j++) bv[j] = bp ? bp[lcol + j] : 0.f;
#pragma unroll
                for (int it = 0; it < 4; it++) {
                    int rr = it * 16 + rsub;
                    int grow = bm + wm + rr;
                    float v0 = wb[rr * 34 + c8 + 0] + bv[0];
                    float v1 = wb[rr * 34 + c8 + 1] + bv[1];
                    float v2 = wb[rr * 34 + c8 + 2] + bv[2];
                    float v3 = wb[rr * 34 + c8 + 3] + bv[3];
                    float v4 = wb[rr * 34 + c8 + 4] + bv[4];
                    float v5 = wb[rr * 34 + c8 + 5] + bv[5];
                    float v6 = wb[rr * 34 + c8 + 6] + bv[6];
                    float v7 = wb[rr * 34 + c8 + 7] + bv[7];
                    uint4 o;
                    o.x = (unsigned)f2bf(v0) | ((unsigned)f2bf(v1) << 16);
                    o.y = (unsigned)f2bf(v2) | ((unsigned)f2bf(v3) << 16);
                    o.z = (unsigned)f2bf(v4) | ((unsigned)f2bf(v5) << 16);
                    o.w = (unsigned)f2bf(v6) | ((unsigned)f2bf(v7) << 16);
                    if (grow < M) *(uint4*)(C0 + (size_t)grow * ldc + colbase) = o;
                }
            } else {
                int rsub = lane >> 3, c4 = (lane & 7) * 4;
                int gcol = wn + h * 32 + c4;
                float bv[4];
#pragma unroll
                for (int j = 0; j < 4; j++) bv[j] = bp[gcol + j];
#pragma unroll
                for (int it = 0; it < 8; it++) {
                    int rr = it * 8 + rsub;
                    int grow = bm + wm + rr;
                    float4 o;
                    o.x = wb[rr * 34 + c4 + 0] + bv[0];
                    o.y = wb[rr * 34 + c4 + 1] + bv[1];
                    o.z = wb[rr * 34 + c4 + 2] + bv[2];
                    o.w = wb[rr * 34 + c4 + 3] + bv[3];
                    if (grow < M) *(float4*)(C1 + (size_t)grow * 128 + gcol) = o;
                }
            }
            asm volatile("s_waitcnt lgkmcnt(0)" ::: "memory");
        }
    }
}

// ================= LayerNorm(256)+ReLU+add, bf16 I/O, optional fp8 shadow out =================
__global__ __launch_bounds__(256) void ln_fuse2(const unsigned short* __restrict__ u, int ustride,
                                                const unsigned short* __restrict__ a, int astride,
                                                const float* __restrict__ g, const float* __restrict__ b,
                                                unsigned short* __restrict__ out, int ostride,
                                                unsigned char* __restrict__ h8, int N) {
    int row = (blockIdx.x * blockDim.x + threadIdx.x) >> 6;
    int lane = threadIdx.x & 63;
    if (row >= N) return;
    uint2 uv = *(const uint2*)(u + (size_t)row * ustride + lane * 4);
    float v0 = bf2f_lo(uv.x), v1 = bf2f_hi(uv.x), v2 = bf2f_lo(uv.y), v3 = bf2f_hi(uv.y);
    float s = (v0 + v1) + (v2 + v3);
    float sq = (v0 * v0 + v1 * v1) + (v2 * v2 + v3 * v3);
    for (int off = 1; off < 64; off <<= 1) {
        s += __shfl_xor(s, off, 64);
        sq += __shfl_xor(sq, off, 64);
    }
    float mu = s * (1.f / 256.f);
    float var = sq * (1.f / 256.f) - mu * mu;
    float rs = rsqrtf(var + 1e-5f);
    float4 gv = *(const float4*)(g + lane * 4);
    float4 bv = *(const float4*)(b + lane * 4);
    uint2 av = *(const uint2*)(a + (size_t)row * astride + lane * 4);
    float a0 = bf2f_lo(av.x), a1 = bf2f_hi(av.x), a2 = bf2f_lo(av.y), a3 = bf2f_hi(av.y);
    float o0 = fmaxf((v0 - mu) * rs * gv.x + bv.x, 0.f) + a0;
    float o1 = fmaxf((v1 - mu) * rs * gv.y + bv.y, 0.f) + a1;
    float o2 = fmaxf((v2 - mu) * rs * gv.z + bv.z, 0.f) + a2;
    float o3 = fmaxf((v3 - mu) * rs * gv.w + bv.w, 0.f) + a3;
    ushort4 o;
    o.x = f2bf(o0); o.y = f2bf(o1); o.z = f2bf(o2); o.w = f2bf(o3);
    *(ushort4*)(out + (size_t)row * ostride + lane * 4) = o;
    if (h8) {
        unsigned wpk = 0;
        wpk = __builtin_amdgcn_cvt_pk_fp8_f32(o0, o1, wpk, false);
        wpk = __builtin_amdgcn_cvt_pk_fp8_f32(o2, o3, wpk, true);
        *(unsigned*)(h8 + (size_t)row * 256 + lane * 4) = wpk;
    }
}

// ================= launch =================
extern "C" void kernel_launch(void* const* d_in, const int* in_sizes, int n_in,
                              void* d_out, int out_size, void* d_ws, size_t ws_size,
                              hipStream_t stream) {
    const float* x   = (const float*)d_in[0];
    const int*   ei  = (const int*)d_in[1];
    const float* W1l = (const float*)d_in[2];
    const float* b1l = (const float*)d_in[3];
    const float* W1r = (const float*)d_in[4];
    const float* g1  = (const float*)d_in[5];
    const float* be1 = (const float*)d_in[6];
    const float* Wsk = (const float*)d_in[7];
    const float* bsk = (const float*)d_in[8];
    const float* W2l = (const float*)d_in[9];
    const float* b2l = (const float*)d_in[10];
    const float* W2r = (const float*)d_in[11];
    const float* g2  = (const float*)d_in[12];
    const float* be2 = (const float*)d_in[13];
    const float* W3l = (const float*)d_in[14];
    const float* b3l = (const float*)d_in[15];
    const float* W3r = (const float*)d_in[16];

    const int N = in_sizes[0] / 128;
    const int E = in_sizes[1] / 2;
    const int* src = ei;
    const int* dst = ei + E;

    char* p = (char*)d_ws;
    auto alloc = [&](size_t bytes) {
        void* r = (void*)p;
        p += (bytes + 255) & ~(size_t)255;
        return r;
    };
    int*   cnt    = (int*)alloc(sizeof(int) * N);
    int*   rowptr = (int*)alloc(sizeof(int) * (N + 1));
    int*   cursor = (int*)alloc(sizeof(int) * N);
    float* invdeg = (float*)alloc(sizeof(float) * N);
    int*   col    = (int*)alloc(sizeof(int) * E);
    int*   bsum   = (int*)alloc(sizeof(int) * 256);
    int*   boff   = (int*)alloc(sizeof(int) * 256);
    unsigned short* A1cat = (unsigned short*)alloc(sizeof(short) * (size_t)N * 256);  // [agg1|x]; later t3
    unsigned short* A2cat = (unsigned short*)alloc(sizeof(short) * (size_t)N * 512);  // [agg2|h] -> [h2|h]
    unsigned short* U1    = (unsigned short*)alloc(sizeof(short) * (size_t)N * 512);  // [u1|s] bf16; later u2
    float* r3 = (float*)alloc(sizeof(float) * (size_t)N * 128);
    unsigned char* H8 = (unsigned char*)alloc((size_t)N * 256);                       // fp8 h shadow
    unsigned char* X8 = (unsigned char*)alloc((size_t)N * 128);                       // fp8 x shadow
    unsigned short* WtC = (unsigned short*)alloc(sizeof(short) * 512 * 256);
    unsigned short* Wt2 = (unsigned short*)alloc(sizeof(short) * 256 * 512);
    unsigned short* Wt3 = (unsigned short*)alloc(sizeof(short) * 256 * 256);
    float* biasC = (float*)alloc(sizeof(float) * 512);
    unsigned short* t3 = A1cat;
    unsigned short* u2 = U1;

    // ---- CSR build ----
    hipMemsetAsync(cnt, 0, sizeof(int) * N, stream);
    hist_kernel<<<(E + 255) / 256, 256, 0, stream>>>(dst, cnt, E);
    int NB = (N + SCAN_CHUNK - 1) / SCAN_CHUNK;
    scan_blocksums<<<NB, 256, 0, stream>>>(cnt, bsum, N);
    scan_bsums<<<1, 256, 0, stream>>>(bsum, boff, NB, rowptr, N, E);
    scan_final<<<NB, 256, 0, stream>>>(cnt, boff, rowptr, cursor, invdeg, N);
    scatter_kernel<<<(E + 255) / 256, 256, 0, stream>>>(src, dst, cursor, col, E);

    // ---- prep ----
    prep_weights<<<(328192 + 255) / 256, 256, 0, stream>>>(W1l, W1r, Wsk, W2l, W2r, W3l, W3r,
                                                           b1l, bsk, WtC, Wt2, Wt3, biasC);
    cvt_x2<<<((N * 32) + 255) / 256, 256, 0, stream>>>(x, A1cat, X8, N * 32);

    int aggBlocks = (N + 3) / 4;
    int mBlocks = (N + 127) / 128;

    // ---- layer 1 ----
    agg_fp8_128<<<aggBlocks, 256, 0, stream>>>(rowptr, col, invdeg, X8, A1cat, 256, N);
    // [u1|s] = A1cat @ WtC^T + [b1l|bsk]  (K=256, 512 cols: grid.y=2, 2 panels each)
    gemm_lds2<4, 2, 0><<<dim3(mBlocks, 2), 256, 0, stream>>>(A1cat, 256, WtC, 256, biasC, U1, 512, nullptr, N);
    // h = relu(LN(u1)) + s -> A2cat right half (+ fp8 shadow for layer-2 gather)
    ln_fuse2<<<aggBlocks, 256, 0, stream>>>(U1, 512, U1 + 256, 512, g1, be1, A2cat + 256, 512, H8, N);

    // ---- layer 2 ----
    agg_fp8_256<<<aggBlocks, 256, 0, stream>>>(rowptr, col, invdeg, H8, A2cat, 512, N);
    // u2 = A2cat @ Wt2^T + b2l  (K=512, 256 cols: one block covers both panels)
    gemm_lds2<8, 2, 0><<<dim3(mBlocks, 1), 256, 0, stream>>>(A2cat, 512, Wt2, 512, b2l, u2, 256, nullptr, N);
    ln_fuse2<<<aggBlocks, 256, 0, stream>>>(u2, 256, A2cat + 256, 512, g2, be2, A2cat, 512, nullptr, N);

    // ---- layer 3: one GEMM, panel0 -> t3 (bf16), panel1 -> r3 (fp32+bias) ----
    gemm_lds2<4, 2, 1><<<dim3(mBlocks, 1), 256, 0, stream>>>(A2cat, 512, Wt3, 256, b3l, t3, 128, r3, N);
    agg_final_v3<<<aggBlocks, 256, 0, stream>>>(rowptr, col, invdeg, t3, r3, (float*)d_out, N);
}